// Round 10
// baseline (4754.410 us; speedup 1.0000x reference)
//
#include <hip/hip_runtime.h>
#include <math.h>

#define DM    512
#define SP    1568   // 8*14*14
#define BATCH 32
#define NSTEP 12
#define CPAD  2560   // padded per-batch spatial rows (10*16*16)
#define LDT   40     // kproj-GEMM LDS row stride (bf16)
#define ILS   520    // fused kernel LDS row stride (bf16)
#define NCH   32     // softinfo chunks: 49 rows each

typedef short s16x8 __attribute__((ext_vector_type(8)));
typedef float f32x4 __attribute__((ext_vector_type(4)));

__device__ __forceinline__ float eluf(float x) { return x > 0.f ? x : expf(x) - 1.f; }
__device__ __forceinline__ float b2f(ushort u) {
  union { float f; unsigned i; } v; v.i = ((unsigned)u) << 16; return v.f;
}
__device__ __forceinline__ ushort f2b(float f) {
  union { float f; unsigned i; } v; v.f = f;
  unsigned r = (v.i + 0x7FFFu + ((v.i >> 16) & 1u)) >> 16;
  return (ushort)r;
}

// async global->LDS, 16B per lane; LDS dest must be wave-uniform base
// (lanes land at base + lane*16B); global src is per-lane.
__device__ __forceinline__ void glds16(ushort* l, const ushort* g) {
  __builtin_amdgcn_global_load_lds(
      (const __attribute__((address_space(1))) void*)g,
      (__attribute__((address_space(3))) void*)l, 16, 0, 0);
}

// ---------------------------------------------------------------------------
// NUMERICS CONSTRAINT (measured R9): the recurrent-path weights (Wci, Wm,
// Wu, Wwrite, Wcat) must stay fp32 — bf16-quantizing them flipped the
// 12-step attention recurrence (absmax 0.83 vs 0.02 threshold). Only the
// feed-forward bulk tensors (know/kproj/befft/wc2t, conv weights) are bf16.
// ---------------------------------------------------------------------------
__global__ void k_zero(uint4* __restrict__ p, long n16) {
  long stride = (long)gridDim.x * blockDim.x;
  for (long i = (long)blockIdx.x * blockDim.x + threadIdx.x; i < n16; i += stride)
    p[i] = make_uint4(0, 0, 0, 0);
}

// image [32][256][1568] fp32 -> NHWC padded bf16 [b][2560][256] (interior only)
__global__ __launch_bounds__(256) void k_padimg(const float* __restrict__ img,
                                               ushort* __restrict__ xp) {
  const int b = blockIdx.x, s0 = blockIdx.y * 32;   // grid (32, 49)
  __shared__ float T[256][33];
  const int t = threadIdx.x;
  const int so = t & 31, cg = t >> 5;               // 8 ci-groups of 32
#pragma unroll 4
  for (int i = 0; i < 32; i++) {
    int ci = cg * 32 + i;
    T[ci][so] = img[((size_t)(b * 256 + ci)) * SP + s0 + so];
  }
  __syncthreads();
#pragma unroll 4
  for (int si = 0; si < 32; si++) {
    int s = s0 + si;
    int z = s / 196, r = s - z * 196, y = r / 14, x = r - y * 14;
    int p = (z + 1) * 256 + (y + 1) * 16 + (x + 1);
    xp[((size_t)b * CPAD + p) * 256 + t] = f2b(T[t][si]);
  }
}

// conv weights [co][ci][27] fp32 -> tap-major bf16 [co][tap*CIN+ci]
template <int CIN>
__global__ __launch_bounds__(256) void k_cvtw(const float* __restrict__ w,
                                              ushort* __restrict__ o) {
  const int co = blockIdx.x;           // 512 blocks
  const int KK = 27 * CIN;
  __shared__ ushort tmp[27 * CIN];
  const int t = threadIdx.x;
  for (int i = t; i < KK; i += 256)
    tmp[i] = f2b(w[(size_t)co * KK + i]);      // src linear: i = ci*27+tap
  __syncthreads();
  for (int i = t; i < KK; i += 256) {
    int tap = i / CIN, ci = i - tap * CIN;     // dst linear: i = tap*CIN+ci
    o[(size_t)co * KK + i] = tmp[ci * 27 + tap];
  }
}

// [512][512] fp32 -> transposed bf16 [n][k]
__global__ void k_cvtT(const float* __restrict__ w, ushort* __restrict__ o) {
  int idx = blockIdx.x * 256 + threadIdx.x;   // < 512*512
  int n = idx >> 9, k = idx & 511;
  o[idx] = f2b(w[(size_t)k * 512 + n]);
}

// ---------------------------------------------------------------------------
// MFMA conv3d (unchanged: gload_lds + XOR involution + XCD swizzle)
// ---------------------------------------------------------------------------
template <int CIN, int ISCONV1>
__global__ __launch_bounds__(256) void k_convm(
    const ushort* __restrict__ W, const ushort* __restrict__ Xp,
    const float* __restrict__ bias, ushort* __restrict__ Y)
{
  const int KK = CIN * 27;
  const int id = blockIdx.x;            // 0..1663
  const int g = id & 7, r = id >> 3;    // 8 XCD groups x 208
  const int b  = g * 4 + (r / 52);
  const int rr = r % 52;
  const int m0 = (rr / 13) * 128;
  const int n0 = (rr % 13) * 128;
  __shared__ __align__(16) ushort As[128 * 64];
  __shared__ __align__(16) ushort Bs[128 * 64];
  const int t = threadIdx.x;
  const int lane = t & 63, wid = t >> 6;
  const int wm = (wid >> 1) * 64, wn = (wid & 1) * 64;
  const int l15 = lane & 15, quad = lane >> 4;
  const int wrow = lane >> 3, wslot = lane & 7;  // staging row/slot in wave

  int padrow[4]; int arow[4], gco[4];
#pragma unroll
  for (int i = 0; i < 4; i++) {
    int row = wid * 32 + i * 8 + wrow;       // 0..127 within tile
    arow[i] = row;
    gco[i] = (wslot ^ (row & 7)) * 8;        // inverse-swizzled chunk offset
    int n = n0 + row;
    if (n >= SP) n = SP - 1;                 // clamp: outputs there never written
    int z = n / 196, rm = n - z * 196, y = rm / 14, x = rm - y * 14;
    padrow[i] = z * 256 + y * 16 + x;        // window-start index in padded space
  }

  f32x4 acc[4][4];
#pragma unroll
  for (int i = 0; i < 4; i++)
#pragma unroll
    for (int j = 0; j < 4; j++) acc[i][j] = (f32x4){0.f, 0.f, 0.f, 0.f};

  for (int k0 = 0; k0 < KK; k0 += 64) {
#pragma unroll
    for (int i = 0; i < 4; i++)
      glds16(&As[(wid * 32 + i * 8) * 64],
             &W[(size_t)(m0 + arow[i]) * KK + k0 + gco[i]]);
    {   // B tile: fixed tap, NHWC, 64 ci, direct-to-LDS (gathered rows)
      int tap = k0 / CIN, ci0 = k0 - tap * CIN;
      int dz = tap / 9, rr2 = tap - dz * 9, dy = rr2 / 3, dx = rr2 - dy * 3;
      int tofs = dz * 256 + dy * 16 + dx;
      const ushort* src = Xp + (size_t)b * CPAD * CIN + ci0;
#pragma unroll
      for (int i = 0; i < 4; i++)
        glds16(&Bs[(wid * 32 + i * 8) * 64],
               &src[(size_t)(padrow[i] + tofs) * CIN + gco[i]]);
    }
    __syncthreads();   // compiler drains vmcnt(0) before s_barrier
#pragma unroll
    for (int sub = 0; sub < 2; sub++) {
      s16x8 af[4], bfr[4];
#pragma unroll
      for (int i = 0; i < 4; i++) {
        int row = wm + i * 16 + l15;
        int c = sub * 4 + quad;
        af[i] = *(const s16x8*)&As[row * 64 + ((c ^ (row & 7)) * 8)];
      }
#pragma unroll
      for (int j = 0; j < 4; j++) {
        int row = wn + j * 16 + l15;
        int c = sub * 4 + quad;
        bfr[j] = *(const s16x8*)&Bs[row * 64 + ((c ^ (row & 7)) * 8)];
      }
#pragma unroll
      for (int i = 0; i < 4; i++)
#pragma unroll
        for (int j = 0; j < 4; j++)
          acc[i][j] = __builtin_amdgcn_mfma_f32_16x16x32_bf16(af[i], bfr[j], acc[i][j], 0, 0, 0);
    }
    __syncthreads();
  }

  int nout[4]; size_t obase[4];
#pragma unroll
  for (int j = 0; j < 4; j++) {
    int n = n0 + wn + j * 16 + l15;
    nout[j] = n; obase[j] = 0;
    if (n < SP) {
      if (ISCONV1) {
        int z = n / 196, rm = n - z * 196, y = rm / 14, x = rm - y * 14;
        obase[j] = ((size_t)b * CPAD + z * 256 + y * 16 + x + 273) * 512;
      } else {
        obase[j] = ((size_t)b * SP + n) * DM;
      }
    }
  }
#pragma unroll
  for (int i = 0; i < 4; i++) {
    int cob = m0 + wm + i * 16 + quad * 4;
    float4 bb = *(const float4*)&bias[cob];
#pragma unroll
    for (int j = 0; j < 4; j++) {
      if (nout[j] < SP) {
        ushort4 o;
        o.x = f2b(eluf(acc[i][j][0] + bb.x));
        o.y = f2b(eluf(acc[i][j][1] + bb.y));
        o.z = f2b(eluf(acc[i][j][2] + bb.z));
        o.w = f2b(eluf(acc[i][j][3] + bb.w));
        *(ushort4*)&Y[obase[j] + cob] = o;
      }
    }
  }
}

// ---------------------------------------------------------------------------
// MFMA GEMM: kproj = know @ WkT + bk (unchanged, XCD-swizzled)
// ---------------------------------------------------------------------------
__global__ __launch_bounds__(256) void k_gemmm(
    const ushort* __restrict__ A0, const ushort* __restrict__ Bt,
    const float* __restrict__ bias, ushort* __restrict__ Cv)
{
  const int id = blockIdx.x;            // 0..1663
  const int g = id & 7, r = id >> 3;
  const int bq = g * 4 + (r / 52);
  const int rr = r % 52;
  const int n0 = (rr / 13) * 128;
  const int m0 = (rr % 13) * 128;
  const ushort* A = A0 + (size_t)bq * SP * DM;
  __shared__ __align__(16) ushort As[128 * LDT];
  __shared__ __align__(16) ushort Bs[128 * LDT];
  const int t = threadIdx.x;
  const int lane = t & 63, wid = t >> 6;
  const int wm = (wid >> 1) * 64, wn = (wid & 1) * 64;
  const int l15 = lane & 15, quad = lane >> 4;
  f32x4 acc[4][4];
#pragma unroll
  for (int i = 0; i < 4; i++)
#pragma unroll
    for (int j = 0; j < 4; j++) acc[i][j] = (f32x4){0.f, 0.f, 0.f, 0.f};

  for (int k0 = 0; k0 < DM; k0 += 32) {
#pragma unroll
    for (int i = 0; i < 2; i++) {
      int f = t + i * 256;
      int row = f >> 2, ko = (f & 3) * 8;
      int mg = m0 + row;
      uint4 v = make_uint4(0, 0, 0, 0);
      if (mg < SP) v = *(const uint4*)&A[(size_t)mg * DM + k0 + ko];
      *(uint4*)&As[row * LDT + ko] = v;
      uint4 w = *(const uint4*)&Bt[(size_t)(n0 + row) * DM + k0 + ko];
      *(uint4*)&Bs[row * LDT + ko] = w;
    }
    __syncthreads();
    s16x8 af[4], bfr[4];
#pragma unroll
    for (int i = 0; i < 4; i++)
      af[i] = *(const s16x8*)&As[(wm + i * 16 + l15) * LDT + quad * 8];
#pragma unroll
    for (int j = 0; j < 4; j++)
      bfr[j] = *(const s16x8*)&Bs[(wn + j * 16 + l15) * LDT + quad * 8];
#pragma unroll
    for (int i = 0; i < 4; i++)
#pragma unroll
      for (int j = 0; j < 4; j++)
        acc[i][j] = __builtin_amdgcn_mfma_f32_16x16x32_bf16(af[i], bfr[j], acc[i][j], 0, 0, 0);
    __syncthreads();
  }

  ushort* C = Cv + (size_t)bq * SP * DM;
#pragma unroll
  for (int j = 0; j < 4; j++) {
    int n = n0 + wn + j * 16 + l15;
    float bb = bias[n];
#pragma unroll
    for (int i = 0; i < 4; i++) {
      int mb = m0 + wm + i * 16 + quad * 4;
#pragma unroll
      for (int r2 = 0; r2 < 4; r2++) {
        int m = mb + r2;
        if (m < SP) C[(size_t)m * DM + n] = f2b(acc[i][j][r2] + bb);
      }
    }
  }
}

// ---------------------------------------------------------------------------
// Fused ReadUnit GEMM pair v18 — v16 structure (LDS alias, 2 blocks/CU) +
// kproj staging via global_load_lds (each Af row = 1024B = 64 lanes x 16B,
// wave-uniform LDS base, per-lane global src, OOB rows clamped — outputs
// masked). This is the one change kept from v17; recurrent weights revert
// to fp32 per the R9 numerics constraint.
// ---------------------------------------------------------------------------
__global__ __launch_bounds__(512, 4) void k_fused12(
    const ushort* __restrict__ kproj, const ushort* __restrict__ befft,
    const ushort* __restrict__ wc2t, const float* __restrict__ bcat,
    const float* __restrict__ bcat2, const float* __restrict__ cbuf,
    const float* __restrict__ raw, float* __restrict__ rl)
{
  extern __shared__ __align__(16) char smem[];
  ushort* Af  = (ushort*)smem;                 // 64*520 (kproj tile, then Il)
  float*  red = (float*)(Af + 64 * ILS);       // 64*8

  const int tile = blockIdx.x;                 // 0..799
  const int g = tile & 7, r = tile >> 3;       // r in 0..99
  const int b  = g * 4 + (r / 25);
  const int m0 = (r % 25) * 64;
  const int t  = threadIdx.x;
  const int lane = t & 63, w = t >> 6;         // 8 waves
  const int l15 = lane & 15, quad = lane >> 4;

  const ushort* kpb = kproj + (size_t)b * SP * DM;
#pragma unroll
  for (int i = 0; i < 8; i++) {
    int row = w * 8 + i;                       // wave-uniform
    int mg = m0 + row;
    if (mg >= SP) mg = SP - 1;                 // clamp (outputs masked later)
    glds16(&Af[row * ILS], &kpb[(size_t)mg * DM + lane * 8]);
  }
  __syncthreads();   // drains vmcnt(0)

  // ---- stage A: each wave covers n1 = w*64 .. w*64+63 ----
  const ushort* bfb = befft + (size_t)b * DM * DM;
  f32x4 acc[4][4];
#pragma unroll
  for (int i = 0; i < 4; i++)
#pragma unroll
    for (int j = 0; j < 4; j++) acc[i][j] = (f32x4){0.f, 0.f, 0.f, 0.f};
#pragma unroll 2
  for (int k0 = 0; k0 < DM; k0 += 32) {
    s16x8 bf[4], af[4];
#pragma unroll
    for (int j = 0; j < 4; j++)
      bf[j] = *(const s16x8*)&bfb[(size_t)(w * 64 + j * 16 + l15) * DM + k0 + quad * 8];
#pragma unroll
    for (int i = 0; i < 4; i++)
      af[i] = *(const s16x8*)&Af[(i * 16 + l15) * ILS + k0 + quad * 8];
#pragma unroll
    for (int i = 0; i < 4; i++)
#pragma unroll
      for (int j = 0; j < 4; j++)
        acc[i][j] = __builtin_amdgcn_mfma_f32_16x16x32_bf16(af[i], bf[j], acc[i][j], 0, 0, 0);
  }
  __syncthreads();   // all Af reads complete before Il overwrites it

#pragma unroll
  for (int j = 0; j < 4; j++) {
    int n1 = w * 64 + j * 16 + l15;
    float bc = bcat[n1];
#pragma unroll
    for (int i = 0; i < 4; i++)
#pragma unroll
      for (int r2 = 0; r2 < 4; r2++)
        Af[(i * 16 + quad * 4 + r2) * ILS + n1] = f2b(eluf(acc[i][j][r2] + bc));
  }
  __syncthreads();

  // ---- stage B: each wave covers n2 = w*64 .. w*64+63 ----
  f32x4 acc2[4][4];
#pragma unroll
  for (int i = 0; i < 4; i++)
#pragma unroll
    for (int j = 0; j < 4; j++) acc2[i][j] = (f32x4){0.f, 0.f, 0.f, 0.f};
#pragma unroll 2
  for (int kk = 0; kk < DM; kk += 32) {
    s16x8 af[4], bf[4];
#pragma unroll
    for (int i = 0; i < 4; i++)
      af[i] = *(const s16x8*)&Af[(i * 16 + l15) * ILS + kk + quad * 8];
#pragma unroll
    for (int j = 0; j < 4; j++)
      bf[j] = *(const s16x8*)&wc2t[(size_t)(w * 64 + j * 16 + l15) * DM + kk + quad * 8];
#pragma unroll
    for (int i = 0; i < 4; i++)
#pragma unroll
      for (int j = 0; j < 4; j++)
        acc2[i][j] = __builtin_amdgcn_mfma_f32_16x16x32_bf16(af[i], bf[j], acc2[i][j], 0, 0, 0);
  }

  // ---- epilogue: rl[m] = sum_n elu((acc2 + bcat2)*c)*raw ----
  float epi[16];
#pragma unroll
  for (int e = 0; e < 16; e++) epi[e] = 0.f;
#pragma unroll
  for (int j = 0; j < 4; j++) {
    int n2 = w * 64 + j * 16 + l15;
    float b2 = bcat2[n2], cc = cbuf[(size_t)b * DM + n2], rw = raw[n2];
#pragma unroll
    for (int i = 0; i < 4; i++)
#pragma unroll
      for (int r2 = 0; r2 < 4; r2++)
        epi[i * 4 + r2] += eluf((acc2[i][j][r2] + b2) * cc) * rw;
  }
#pragma unroll
  for (int d2 = 1; d2 < 16; d2 <<= 1)
#pragma unroll
    for (int e = 0; e < 16; e++) epi[e] += __shfl_xor(epi[e], d2, 64);
  if (l15 == 0) {
#pragma unroll
    for (int i = 0; i < 4; i++)
#pragma unroll
      for (int r2 = 0; r2 < 4; r2++)
        red[(i * 16 + quad * 4 + r2) * 8 + w] = epi[i * 4 + r2];
  }
  __syncthreads();
  if (t < 64) {
    int m = m0 + t;
    if (m < SP) {
      float s = 0.f;
#pragma unroll
      for (int q = 0; q < 8; q++) s += red[t * 8 + q];
      rl[(size_t)b * SP + m] = s;
    }
  }
}

// ---------------------------------------------------------------------------
// Per-step fold: befft[b][n][k] = bf16(mp[b][k]*Wcat[k][n] + Wcat[512+k][n])
// (fp32 Wcat — R9 constraint)
// ---------------------------------------------------------------------------
__global__ __launch_bounds__(256) void k_prefold(
    const float* __restrict__ Wcat, const float* __restrict__ mp,
    ushort* __restrict__ Bf)
{
  const int k0 = blockIdx.x * 64, n0 = blockIdx.y * 64;
  const int bbase = blockIdx.z * 8;
  __shared__ float S1[64][68], S2[64][68];
  const int t = threadIdx.x;
#pragma unroll
  for (int i = 0; i < 4; i++) {
    int f = t + i * 256;
    int kk = f >> 4, nn2 = (f & 15) * 4;
    float4 a = *(const float4*)&Wcat[(size_t)(k0 + kk) * DM + n0 + nn2];
    float4 c = *(const float4*)&Wcat[(size_t)(DM + k0 + kk) * DM + n0 + nn2];
    *(float4*)&S1[kk][nn2] = a;
    *(float4*)&S2[kk][nn2] = c;
  }
  __syncthreads();
  const int n = t >> 2, kseg = (t & 3) * 16;
  for (int bq = 0; bq < 8; bq++) {
    const float* mpb = mp + (size_t)(bbase + bq) * DM + k0 + kseg;
    ushort* out = Bf + ((size_t)(bbase + bq) * DM + n0 + n) * DM + k0 + kseg;
#pragma unroll
    for (int g = 0; g < 4; g++) {
      ushort4 o;
      o.x = f2b(mpb[g * 4 + 0] * S1[kseg + g * 4 + 0][n] + S2[kseg + g * 4 + 0][n]);
      o.y = f2b(mpb[g * 4 + 1] * S1[kseg + g * 4 + 1][n] + S2[kseg + g * 4 + 1][n]);
      o.z = f2b(mpb[g * 4 + 2] * S1[kseg + g * 4 + 2][n] + S2[kseg + g * 4 + 2][n]);
      o.w = f2b(mpb[g * 4 + 3] * S1[kseg + g * 4 + 3][n] + S2[kseg + g * 4 + 3][n]);
      *(ushort4*)&out[g * 4] = o;
    }
  }
}

// ---------------------------------------------------------------------------
// Control unit (R5/R8-measured version — fp32 weights, 512 threads)
// ---------------------------------------------------------------------------
__global__ __launch_bounds__(512) void k_ctrl(
    const float* cin, const float* __restrict__ min_,
    const float* __restrict__ Wci, const float* __restrict__ bci,
    const float* __restrict__ Wu_i, const float* __restrict__ bu_i,
    const float* __restrict__ caw, const float* __restrict__ concepts,
    const float* __restrict__ Wm, const float* __restrict__ bm,
    float* cout, float* __restrict__ mpout)
{
  const int b = blockIdx.x, t = threadIdx.x;   // 512 threads
  __shared__ float sc[512], sm[512], sq0[512], sqa[512], scl[80], red[512];
  sc[t] = cin[b * DM + t];
  sm[t] = min_[b * DM + t];
  __syncthreads();
  {
    const int d = t;
    float a0 = bci[d], a1 = 0.f, a2 = 0.f, a3 = 0.f;
    for (int k = 0; k < 512; k += 4) {
      a0 = fmaf(sc[k + 0], Wci[(size_t)(k + 0) * DM + d], a0);
      a1 = fmaf(sc[k + 1], Wci[(size_t)(k + 1) * DM + d], a1);
      a2 = fmaf(sc[k + 2], Wci[(size_t)(k + 2) * DM + d], a2);
      a3 = fmaf(sc[k + 3], Wci[(size_t)(k + 3) * DM + d], a3);
    }
    for (int k = 0; k < 512; k += 4) {
      a0 = fmaf(sm[k + 0], Wci[(size_t)(512 + k + 0) * DM + d], a0);
      a1 = fmaf(sm[k + 1], Wci[(size_t)(512 + k + 1) * DM + d], a1);
      a2 = fmaf(sm[k + 2], Wci[(size_t)(512 + k + 2) * DM + d], a2);
      a3 = fmaf(sm[k + 3], Wci[(size_t)(512 + k + 3) * DM + d], a3);
    }
    sq0[d] = tanhf((a0 + a1) + (a2 + a3));
    float p0 = bm[d], p1 = 0.f, p2 = 0.f, p3 = 0.f;
    for (int k = 0; k < 512; k += 4) {
      p0 = fmaf(sm[k + 0], Wm[(size_t)(k + 0) * DM + d], p0);
      p1 = fmaf(sm[k + 1], Wm[(size_t)(k + 1) * DM + d], p1);
      p2 = fmaf(sm[k + 2], Wm[(size_t)(k + 2) * DM + d], p2);
      p3 = fmaf(sm[k + 3], Wm[(size_t)(k + 3) * DM + d], p3);
    }
    mpout[b * DM + d] = (p0 + p1) + (p2 + p3);
  }
  __syncthreads();
  {
    const int d = t;
    float a0 = bu_i[d], a1 = 0.f, a2 = 0.f, a3 = 0.f;
    for (int k = 0; k < 512; k += 4) {
      a0 = fmaf(sq0[k + 0], Wu_i[(size_t)(k + 0) * DM + d], a0);
      a1 = fmaf(sq0[k + 1], Wu_i[(size_t)(k + 1) * DM + d], a1);
      a2 = fmaf(sq0[k + 2], Wu_i[(size_t)(k + 2) * DM + d], a2);
      a3 = fmaf(sq0[k + 3], Wu_i[(size_t)(k + 3) * DM + d], a3);
    }
    sqa[d] = ((a0 + a1) + (a2 + a3)) * caw[d];
  }
  __syncthreads();
  float myl = -INFINITY;
  if (t < 80) {
    float a0 = 0.f, a1 = 0.f, a2 = 0.f, a3 = 0.f;
    for (int d = 0; d < 512; d += 4) {
      a0 = fmaf(sqa[d + 0], concepts[(size_t)t * DM + d + 0], a0);
      a1 = fmaf(sqa[d + 1], concepts[(size_t)t * DM + d + 1], a1);
      a2 = fmaf(sqa[d + 2], concepts[(size_t)t * DM + d + 2], a2);
      a3 = fmaf(sqa[d + 3], concepts[(size_t)t * DM + d + 3], a3);
    }
    float a = (a0 + a1) + (a2 + a3);
    scl[t] = a; myl = a;
  }
  red[t] = myl; __syncthreads();
  for (int s = 256; s > 0; s >>= 1) { if (t < s) red[t] = fmaxf(red[t], red[t + s]); __syncthreads(); }
  float mx = red[0]; __syncthreads();
  float e = 0.f;
  if (t < 80) e = expf(scl[t] - mx);
  red[t] = e; __syncthreads();
  for (int s = 256; s > 0; s >>= 1) { if (t < s) red[t] += red[t + s]; __syncthreads(); }
  float inv = 1.f / red[0]; __syncthreads();
  if (t < 80) scl[t] = e * inv;
  __syncthreads();
  {
    const int d = t;
    float a0 = 0.f, a1 = 0.f, a2 = 0.f, a3 = 0.f;
    for (int l = 0; l < 80; l += 4) {
      a0 = fmaf(scl[l + 0], concepts[(size_t)(l + 0) * DM + d], a0);
      a1 = fmaf(scl[l + 1], concepts[(size_t)(l + 1) * DM + d], a1);
      a2 = fmaf(scl[l + 2], concepts[(size_t)(l + 2) * DM + d], a2);
      a3 = fmaf(scl[l + 3], concepts[(size_t)(l + 3) * DM + d], a3);
    }
    cout[b * DM + d] = (a0 + a1) + (a2 + a3);
  }
}

// ---------------------------------------------------------------------------
// Fused read softmax + info partial (unchanged, NCH=32)
// ---------------------------------------------------------------------------
__global__ __launch_bounds__(256) void k_softinfo(
    const float* __restrict__ rl, const ushort* __restrict__ know,
    float* __restrict__ ipart)
{
  const int b = blockIdx.x, c = blockIdx.y, t = threadIdx.x;  // c in 0..31
  __shared__ float red[256];
  __shared__ float rprob[49];
  float vals[7]; float vmax = -INFINITY;
#pragma unroll
  for (int q = 0; q < 7; q++) {
    int s = t + q * 256;
    float v = (s < SP) ? rl[(size_t)b * SP + s] : -INFINITY;
    vals[q] = v; vmax = fmaxf(vmax, v);
  }
  red[t] = vmax; __syncthreads();
  for (int s = 128; s > 0; s >>= 1) { if (t < s) red[t] = fmaxf(red[t], red[t + s]); __syncthreads(); }
  float mx = red[0]; __syncthreads();
  float lsum = 0.f;
#pragma unroll
  for (int q = 0; q < 7; q++) {
    int s = t + q * 256;
    lsum += (s < SP) ? expf(vals[q] - mx) : 0.f;
  }
  red[t] = lsum; __syncthreads();
  for (int s = 128; s > 0; s >>= 1) { if (t < s) red[t] += red[t + s]; __syncthreads(); }
  float inv = 1.f / red[0];

  if (t < 49) rprob[t] = expf(rl[(size_t)b * SP + c * 49 + t] - mx) * inv;
  __syncthreads();

  float a0 = 0.f, a1 = 0.f;
  const ushort* kb = know + (size_t)b * SP * DM + (size_t)c * 49 * DM + 2 * t;
  for (int si = 0; si < 49; si++) {
    float r = rprob[si];
    ushort2 kv = *(const ushort2*)&kb[(size_t)si * DM];
    a0 = fmaf(r, b2f(kv.x), a0);
    a1 = fmaf(r, b2f(kv.y), a1);
  }
  ipart[((size_t)b * NCH + c) * DM + 2 * t] = a0;
  ipart[((size_t)b * NCH + c) * DM + 2 * t + 1] = a1;
}

// m_new = [m_old, info] @ Wwrite + bwrite (fp32 weights — R9 constraint)
__global__ __launch_bounds__(256) void k_write(
    const float* __restrict__ mold, const float* __restrict__ ipart,
    const float* __restrict__ Ww, const float* __restrict__ bw,
    float* __restrict__ mnew)
{
  const int b = blockIdx.x, half = blockIdx.y, t = threadIdx.x;
  __shared__ float smo[512], sinfo[512];
  for (int k = t; k < 512; k += 256) {
    smo[k] = mold[b * DM + k];
    float s0 = 0.f, s1 = 0.f, s2 = 0.f, s3 = 0.f;
    for (int c = 0; c < NCH; c += 4) {
      s0 += ipart[((size_t)b * NCH + c + 0) * DM + k];
      s1 += ipart[((size_t)b * NCH + c + 1) * DM + k];
      s2 += ipart[((size_t)b * NCH + c + 2) * DM + k];
      s3 += ipart[((size_t)b * NCH + c + 3) * DM + k];
    }
    sinfo[k] = (s0 + s1) + (s2 + s3);
  }
  __syncthreads();
  int d = half * 256 + t;
  float a0 = bw[d], a1 = 0.f, a2 = 0.f, a3 = 0.f;
  for (int k = 0; k < 512; k += 4) {
    a0 = fmaf(smo[k + 0], Ww[(size_t)(k + 0) * DM + d], a0);
    a1 = fmaf(smo[k + 1], Ww[(size_t)(k + 1) * DM + d], a1);
    a2 = fmaf(smo[k + 2], Ww[(size_t)(k + 2) * DM + d], a2);
    a3 = fmaf(smo[k + 3], Ww[(size_t)(k + 3) * DM + d], a3);
  }
  for (int k = 0; k < 512; k += 4) {
    a0 = fmaf(sinfo[k + 0], Ww[(size_t)(512 + k + 0) * DM + d], a0);
    a1 = fmaf(sinfo[k + 1], Ww[(size_t)(512 + k + 1) * DM + d], a1);
    a2 = fmaf(sinfo[k + 2], Ww[(size_t)(512 + k + 2) * DM + d], a2);
    a3 = fmaf(sinfo[k + 3], Ww[(size_t)(512 + k + 3) * DM + d], a3);
  }
  mnew[b * DM + d] = (a0 + a1) + (a2 + a3);
}

__global__ void k_init(const float* __restrict__ initc, const float* __restrict__ initm,
                       float* __restrict__ cbuf, float* __restrict__ mbuf)
{
  const int b = blockIdx.x, t = threadIdx.x;
  cbuf[b * DM + t] = initc[t];
  mbuf[b * DM + t] = initm[t];
}

__global__ void k_mpo(const float* __restrict__ m, const float* __restrict__ Wproj,
                      const float* __restrict__ bproj, const float* __restrict__ ow,
                      float* __restrict__ mw)
{
  const int b = blockIdx.x, t = threadIdx.x;
  __shared__ float smem[512];
  for (int k = t; k < 512; k += 320) smem[k] = m[b * DM + k];
  __syncthreads();
  if (t < 300) {
    float a0 = bproj[t], a1 = 0.f, a2 = 0.f, a3 = 0.f;
    for (int k = 0; k < 512; k += 4) {
      a0 = fmaf(smem[k + 0], Wproj[(size_t)(k + 0) * 300 + t], a0);
      a1 = fmaf(smem[k + 1], Wproj[(size_t)(k + 1) * 300 + t], a1);
      a2 = fmaf(smem[k + 2], Wproj[(size_t)(k + 2) * 300 + t], a2);
      a3 = fmaf(smem[k + 3], Wproj[(size_t)(k + 3) * 300 + t], a3);
    }
    mw[b * 300 + t] = ((a0 + a1) + (a2 + a3)) * ow[t];
  }
}

__global__ void k_logits(const float* __restrict__ mw, const float* __restrict__ labels,
                         float* __restrict__ logits)
{
  const int b = blockIdx.x, t = threadIdx.x;
  const int a = blockIdx.y * 256 + t;
  __shared__ float smw[300];
  for (int p = t; p < 300; p += 256) smw[p] = mw[b * 300 + p];
  __syncthreads();
  if (a < 1000) {
    float a0 = 0.f, a1 = 0.f, a2 = 0.f, a3 = 0.f;
    for (int p = 0; p < 300; p += 4) {
      a0 = fmaf(smw[p + 0], labels[(size_t)a * 300 + p + 0], a0);
      a1 = fmaf(smw[p + 1], labels[(size_t)a * 300 + p + 1], a1);
      a2 = fmaf(smw[p + 2], labels[(size_t)a * 300 + p + 2], a2);
      a3 = fmaf(smw[p + 3], labels[(size_t)a * 300 + p + 3], a3);
    }
    logits[b * 1000 + a] = (a0 + a1) + (a2 + a3);
  }
}

__global__ void k_softmax_out(const float* __restrict__ logits, float* __restrict__ out)
{
  const int b = blockIdx.x, t = threadIdx.x;
  __shared__ float red[256];
  float v[4]; float vmax = -INFINITY;
#pragma unroll
  for (int q = 0; q < 4; q++) {
    int a = t + q * 256;
    v[q] = (a < 1000) ? logits[b * 1000 + a] : -INFINITY;
    vmax = fmaxf(vmax, v[q]);
  }
  red[t] = vmax; __syncthreads();
  for (int s = 128; s > 0; s >>= 1) { if (t < s) red[t] = fmaxf(red[t], red[t + s]); __syncthreads(); }
  float mx = red[0]; __syncthreads();
  float lsum = 0.f;
#pragma unroll
  for (int q = 0; q < 4; q++) {
    int a = t + q * 256;
    v[q] = (a < 1000) ? expf(v[q] - mx) : 0.f;
    lsum += v[q];
  }
  red[t] = lsum; __syncthreads();
  for (int s = 128; s > 0; s >>= 1) { if (t < s) red[t] += red[t + s]; __syncthreads(); }
  float inv = 1.f / red[0];
#pragma unroll
  for (int q = 0; q < 4; q++) {
    int a = t + q * 256;
    if (a < 1000) out[b * 1000 + a] = v[q] * inv;
  }
}

// ---------------------------------------------------------------------------
extern "C" void kernel_launch(void* const* d_in, const int* in_sizes, int n_in,
                              void* d_out, int out_size, void* d_ws, size_t ws_size,
                              hipStream_t stream)
{
  const float* image    = (const float*)d_in[0];
  const float* concepts = (const float*)d_in[1];
  const float* conv1_w  = (const float*)d_in[2];
  const float* conv1_b  = (const float*)d_in[3];
  const float* conv2_w  = (const float*)d_in[4];
  const float* conv2_b  = (const float*)d_in[5];
  const float* Wci      = (const float*)d_in[6];
  const float* bci      = (const float*)d_in[7];
  const float* Wu       = (const float*)d_in[8];
  const float* bu       = (const float*)d_in[9];
  const float* caw      = (const float*)d_in[10];
  const float* Wk       = (const float*)d_in[12];
  const float* bk       = (const float*)d_in[13];
  const float* Wm       = (const float*)d_in[14];
  const float* bm       = (const float*)d_in[15];
  const float* Wcat     = (const float*)d_in[16];
  const float* bcat     = (const float*)d_in[17];
  const float* Wcat2    = (const float*)d_in[18];
  const float* bcat2    = (const float*)d_in[19];
  const float* raw      = (const float*)d_in[20];
  const float* Wwrite   = (const float*)d_in[22];
  const float* bwrite   = (const float*)d_in[23];
  const float* initc    = (const float*)d_in[24];
  const float* initm    = (const float*)d_in[25];
  const float* Wproj    = (const float*)d_in[26];
  const float* bproj    = (const float*)d_in[27];
  const float* oaw      = (const float*)d_in[28];
  const float* labels   = (const float*)d_in[30];

  char* ws = (char*)d_ws;
  const size_t OFF_KNOW = 0;
  const size_t OFF_XPAD = 51380224;
  const size_t SZ_XPAD  = 83951616;
  const size_t OFF_W    = OFF_XPAD + SZ_XPAD;
  const size_t OFF_WKT  = OFF_W + 14155776;
  const size_t OFF_WC2T = OFF_WKT + 524288;
  size_t off = OFF_WC2T + 524288;
  auto allocB = [&](size_t bytes) {
    void* p = ws + off; off += (bytes + 255) & ~(size_t)255; return p;
  };
  ushort* know   = (ushort*)(ws + OFF_KNOW);
  ushort* imgpad = (ushort*)(ws + OFF_KNOW);                 // stem only
  ushort* xpad1  = (ushort*)(ws + OFF_XPAD);                 // stem only
  ushort* kproj  = (ushort*)(ws + OFF_XPAD);                 // loop
  ushort* befft  = (ushort*)(ws + OFF_XPAD + 51380224);      // loop, 16.78MB
  float*  rl     = (float*) (ws + OFF_XPAD + 68157440);      // loop, 0.2MB
  ushort* w1b    = (ushort*)(ws + OFF_W);
  ushort* w2b    = (ushort*)(ws + OFF_W);
  ushort* wkt    = (ushort*)(ws + OFF_WKT);
  ushort* wc2t   = (ushort*)(ws + OFF_WC2T);
  float* ipart  = (float*)allocB((size_t)BATCH * NCH * DM * 4);
  float* cbuf   = (float*)allocB(BATCH * DM * 4);
  float* mbufA  = (float*)allocB(BATCH * DM * 4);
  float* mbufB  = (float*)allocB(BATCH * DM * 4);
  float* mp     = (float*)allocB(BATCH * DM * 4);
  float* mw     = (float*)allocB(BATCH * 300 * 4);
  float* logits = (float*)allocB(BATCH * 1000 * 4);
  if (off > ws_size) return;  // graceful fail

  const int FUSED_LDS = 64 * ILS * 2 + 64 * 8 * 4;  // 68,608 B -> 2 blocks/CU
  hipFuncSetAttribute((const void*)k_fused12,
                      hipFuncAttributeMaxDynamicSharedMemorySize, FUSED_LDS);

  // --- stem ---
  k_zero<<<4096, 256, 0, stream>>>((uint4*)imgpad, 2625536L);
  k_zero<<<4096, 256, 0, stream>>>((uint4*)xpad1, 5246976L);
  k_padimg<<<dim3(BATCH, 49), 256, 0, stream>>>(image, imgpad);
  k_cvtw<256><<<512, 256, 0, stream>>>(conv1_w, w1b);
  k_cvtT<<<1024, 256, 0, stream>>>(Wk, wkt);
  k_cvtT<<<1024, 256, 0, stream>>>(Wcat2, wc2t);
  k_convm<256, 1><<<1664, 256, 0, stream>>>(w1b, imgpad, conv1_b, xpad1);
  k_cvtw<512><<<512, 256, 0, stream>>>(conv2_w, w2b);
  k_convm<512, 0><<<1664, 256, 0, stream>>>(w2b, xpad1, conv2_b, know);
  k_gemmm<<<1664, 256, 0, stream>>>(know, wkt, bk, kproj);
  k_init<<<BATCH, DM, 0, stream>>>(initc, initm, cbuf, mbufA);

  float* mc = mbufA; float* mn = mbufB;
  for (int i = 0; i < NSTEP; i++) {
    k_ctrl<<<BATCH, 512, 0, stream>>>(cbuf, mc, Wci, bci,
                                      Wu + (size_t)i * DM * DM, bu + i * DM,
                                      caw, concepts, Wm, bm, cbuf, mp);
    k_prefold<<<dim3(8, 8, 4), 256, 0, stream>>>(Wcat, mp, befft);
    k_fused12<<<dim3(800), 512, FUSED_LDS, stream>>>(
        kproj, befft, wc2t, bcat, bcat2, cbuf, raw, rl);
    k_softinfo<<<dim3(BATCH, NCH), 256, 0, stream>>>(rl, know, ipart);
    k_write<<<dim3(BATCH, 2), 256, 0, stream>>>(mc, ipart, Wwrite, bwrite, mn);
    float* tswap = mc; mc = mn; mn = tswap;
  }

  k_mpo<<<BATCH, 320, 0, stream>>>(mc, Wproj, bproj, oaw, mw);
  k_logits<<<dim3(BATCH, 4), 256, 0, stream>>>(mw, labels, logits);
  k_softmax_out<<<BATCH, 256, 0, stream>>>(logits, (float*)d_out);

  (void)in_sizes; (void)n_in; (void)out_size;
}

// Round 11
// 4542.678 us; speedup vs baseline: 1.0466x; 1.0466x over previous
//
#include <hip/hip_runtime.h>
#include <math.h>

#define DM    512
#define SP    1568   // 8*14*14
#define BATCH 32
#define NSTEP 12
#define CPAD  2560   // padded per-batch spatial rows (10*16*16)
#define LDT   40     // kproj-GEMM LDS row stride (bf16)
#define ILS   520    // fused kernel LDS row stride (bf16)
#define NCH   32     // softinfo chunks: 49 rows each

typedef short s16x8 __attribute__((ext_vector_type(8)));
typedef float f32x4 __attribute__((ext_vector_type(4)));

__device__ __forceinline__ float eluf(float x) { return x > 0.f ? x : expf(x) - 1.f; }
__device__ __forceinline__ float b2f(ushort u) {
  union { float f; unsigned i; } v; v.i = ((unsigned)u) << 16; return v.f;
}
__device__ __forceinline__ ushort f2b(float f) {
  union { float f; unsigned i; } v; v.f = f;
  unsigned r = (v.i + 0x7FFFu + ((v.i >> 16) & 1u)) >> 16;
  return (ushort)r;
}

// async global->LDS, 16B per lane; LDS dest must be wave-uniform base
// (lanes land at base + lane*16B); global src is per-lane.
__device__ __forceinline__ void glds16(ushort* l, const ushort* g) {
  __builtin_amdgcn_global_load_lds(
      (const __attribute__((address_space(1))) void*)g,
      (__attribute__((address_space(3))) void*)l, 16, 0, 0);
}

// ---------------------------------------------------------------------------
// NUMERICS CONSTRAINT (measured R9): the recurrent-path weights (Wci, Wm,
// Wu, Wwrite, Wcat) must stay fp32 — bf16-quantizing them flipped the
// 12-step attention recurrence (absmax 0.83 vs 0.02 threshold). Only the
// feed-forward bulk tensors (know/kproj/befft/wc2t, conv weights) are bf16.
// ---------------------------------------------------------------------------
__global__ void k_zero(uint4* __restrict__ p, long n16) {
  long stride = (long)gridDim.x * blockDim.x;
  for (long i = (long)blockIdx.x * blockDim.x + threadIdx.x; i < n16; i += stride)
    p[i] = make_uint4(0, 0, 0, 0);
}

// image [32][256][1568] fp32 -> NHWC padded bf16 [b][2560][256] (interior only)
__global__ __launch_bounds__(256) void k_padimg(const float* __restrict__ img,
                                               ushort* __restrict__ xp) {
  const int b = blockIdx.x, s0 = blockIdx.y * 32;   // grid (32, 49)
  __shared__ float T[256][33];
  const int t = threadIdx.x;
  const int so = t & 31, cg = t >> 5;               // 8 ci-groups of 32
#pragma unroll 4
  for (int i = 0; i < 32; i++) {
    int ci = cg * 32 + i;
    T[ci][so] = img[((size_t)(b * 256 + ci)) * SP + s0 + so];
  }
  __syncthreads();
#pragma unroll 4
  for (int si = 0; si < 32; si++) {
    int s = s0 + si;
    int z = s / 196, r = s - z * 196, y = r / 14, x = r - y * 14;
    int p = (z + 1) * 256 + (y + 1) * 16 + (x + 1);
    xp[((size_t)b * CPAD + p) * 256 + t] = f2b(T[t][si]);
  }
}

// conv weights [co][ci][27] fp32 -> tap-major bf16 [co][tap*CIN+ci]
template <int CIN>
__global__ __launch_bounds__(256) void k_cvtw(const float* __restrict__ w,
                                              ushort* __restrict__ o) {
  const int co = blockIdx.x;           // 512 blocks
  const int KK = 27 * CIN;
  __shared__ ushort tmp[27 * CIN];
  const int t = threadIdx.x;
  for (int i = t; i < KK; i += 256)
    tmp[i] = f2b(w[(size_t)co * KK + i]);      // src linear: i = ci*27+tap
  __syncthreads();
  for (int i = t; i < KK; i += 256) {
    int tap = i / CIN, ci = i - tap * CIN;     // dst linear: i = tap*CIN+ci
    o[(size_t)co * KK + i] = tmp[ci * 27 + tap];
  }
}

// [512][512] fp32 -> transposed bf16 [n][k]
__global__ void k_cvtT(const float* __restrict__ w, ushort* __restrict__ o) {
  int idx = blockIdx.x * 256 + threadIdx.x;   // < 512*512
  int n = idx >> 9, k = idx & 511;
  o[idx] = f2b(w[(size_t)k * 512 + n]);
}

// ---------------------------------------------------------------------------
// MFMA conv3d v19 — tap-outer / ci-inner K loop. R10 counters showed
// MfmaUtil 38 + VALUBusy 50 (88% issue-busy): per K-iter the old loop
// recomputed tap = k0/CIN, /9, /3 and 4x (padrow+tofs)*CIN 64-bit muls —
// ~40 VALU ops vs 16 MFMA (1:1 cycle ratio, matching the counters). Now
// the div chain runs 27x total (tap loop); the ci-inner loop is fully
// unrolled with compile-time c0 so glds16 addresses are running-pointer +
// constant (folds into the instruction offset). K-sequence is identical
// (tap*CIN + c0 == old k0) -> bit-identical accumulation.
// ---------------------------------------------------------------------------
template <int CIN, int ISCONV1>
__global__ __launch_bounds__(256) void k_convm(
    const ushort* __restrict__ W, const ushort* __restrict__ Xp,
    const float* __restrict__ bias, ushort* __restrict__ Y)
{
  const int KK = CIN * 27;
  const int id = blockIdx.x;            // 0..1663
  const int g = id & 7, r = id >> 3;    // 8 XCD groups x 208
  const int b  = g * 4 + (r / 52);
  const int rr = r % 52;
  const int m0 = (rr / 13) * 128;
  const int n0 = (rr % 13) * 128;
  __shared__ __align__(16) ushort As[128 * 64];
  __shared__ __align__(16) ushort Bs[128 * 64];
  const int t = threadIdx.x;
  const int lane = t & 63, wid = t >> 6;
  const int wm = (wid >> 1) * 64, wn = (wid & 1) * 64;
  const int l15 = lane & 15, quad = lane >> 4;
  const int wrow = lane >> 3, wslot = lane & 7;  // staging row/slot in wave

  // per-thread staging rows and running source pointers (fixed per block)
  const ushort* ap[4];   // A: weights, advance by CIN per tap
  const ushort* bp[4];   // B: activations, advance by tofs*CIN per tap
  ushort* alds[4]; ushort* blds[4];
#pragma unroll
  for (int i = 0; i < 4; i++) {
    int row = wid * 32 + i * 8 + wrow;       // 0..127 within tile
    int gco = (wslot ^ (row & 7)) * 8;       // inverse-swizzled chunk offset
    int n = n0 + row;
    if (n >= SP) n = SP - 1;                 // clamp: outputs there never written
    int z = n / 196, rm = n - z * 196, y = rm / 14, x = rm - y * 14;
    int padrow = z * 256 + y * 16 + x;       // window-start index in padded space
    ap[i] = W + (size_t)(m0 + row) * KK + gco;
    bp[i] = Xp + (size_t)b * CPAD * CIN + (size_t)padrow * CIN + gco;
    alds[i] = &As[(wid * 32 + i * 8) * 64];
    blds[i] = &Bs[(wid * 32 + i * 8) * 64];
  }

  f32x4 acc[4][4];
#pragma unroll
  for (int i = 0; i < 4; i++)
#pragma unroll
    for (int j = 0; j < 4; j++) acc[i][j] = (f32x4){0.f, 0.f, 0.f, 0.f};

  for (int tap = 0; tap < 27; tap++) {
    int dz = tap / 9, rr2 = tap - dz * 9, dy = rr2 / 3, dx = rr2 - dy * 3;
    int toff = (dz * 256 + dy * 16 + dx) * CIN;   // wave-uniform
    int aoff = tap * CIN;
#pragma unroll
    for (int c0 = 0; c0 < CIN; c0 += 64) {
#pragma unroll
      for (int i = 0; i < 4; i++)
        glds16(alds[i], ap[i] + aoff + c0);
#pragma unroll
      for (int i = 0; i < 4; i++)
        glds16(blds[i], bp[i] + toff + c0);
      __syncthreads();   // compiler drains vmcnt(0) before s_barrier
#pragma unroll
      for (int sub = 0; sub < 2; sub++) {
        s16x8 af[4], bfr[4];
#pragma unroll
        for (int i = 0; i < 4; i++) {
          int row = wm + i * 16 + l15;
          int c = sub * 4 + quad;
          af[i] = *(const s16x8*)&As[row * 64 + ((c ^ (row & 7)) * 8)];
        }
#pragma unroll
        for (int j = 0; j < 4; j++) {
          int row = wn + j * 16 + l15;
          int c = sub * 4 + quad;
          bfr[j] = *(const s16x8*)&Bs[row * 64 + ((c ^ (row & 7)) * 8)];
        }
#pragma unroll
        for (int i = 0; i < 4; i++)
#pragma unroll
          for (int j = 0; j < 4; j++)
            acc[i][j] = __builtin_amdgcn_mfma_f32_16x16x32_bf16(af[i], bfr[j], acc[i][j], 0, 0, 0);
      }
      __syncthreads();
    }
  }

  int nout[4]; size_t obase[4];
#pragma unroll
  for (int j = 0; j < 4; j++) {
    int n = n0 + wn + j * 16 + l15;
    nout[j] = n; obase[j] = 0;
    if (n < SP) {
      if (ISCONV1) {
        int z = n / 196, rm = n - z * 196, y = rm / 14, x = rm - y * 14;
        obase[j] = ((size_t)b * CPAD + z * 256 + y * 16 + x + 273) * 512;
      } else {
        obase[j] = ((size_t)b * SP + n) * DM;
      }
    }
  }
#pragma unroll
  for (int i = 0; i < 4; i++) {
    int cob = m0 + wm + i * 16 + quad * 4;
    float4 bb = *(const float4*)&bias[cob];
#pragma unroll
    for (int j = 0; j < 4; j++) {
      if (nout[j] < SP) {
        ushort4 o;
        o.x = f2b(eluf(acc[i][j][0] + bb.x));
        o.y = f2b(eluf(acc[i][j][1] + bb.y));
        o.z = f2b(eluf(acc[i][j][2] + bb.z));
        o.w = f2b(eluf(acc[i][j][3] + bb.w));
        *(ushort4*)&Y[obase[j] + cob] = o;
      }
    }
  }
}

// ---------------------------------------------------------------------------
// MFMA GEMM: kproj = know @ WkT + bk (unchanged, XCD-swizzled)
// ---------------------------------------------------------------------------
__global__ __launch_bounds__(256) void k_gemmm(
    const ushort* __restrict__ A0, const ushort* __restrict__ Bt,
    const float* __restrict__ bias, ushort* __restrict__ Cv)
{
  const int id = blockIdx.x;            // 0..1663
  const int g = id & 7, r = id >> 3;
  const int bq = g * 4 + (r / 52);
  const int rr = r % 52;
  const int n0 = (rr / 13) * 128;
  const int m0 = (rr % 13) * 128;
  const ushort* A = A0 + (size_t)bq * SP * DM;
  __shared__ __align__(16) ushort As[128 * LDT];
  __shared__ __align__(16) ushort Bs[128 * LDT];
  const int t = threadIdx.x;
  const int lane = t & 63, wid = t >> 6;
  const int wm = (wid >> 1) * 64, wn = (wid & 1) * 64;
  const int l15 = lane & 15, quad = lane >> 4;
  f32x4 acc[4][4];
#pragma unroll
  for (int i = 0; i < 4; i++)
#pragma unroll
    for (int j = 0; j < 4; j++) acc[i][j] = (f32x4){0.f, 0.f, 0.f, 0.f};

  for (int k0 = 0; k0 < DM; k0 += 32) {
#pragma unroll
    for (int i = 0; i < 2; i++) {
      int f = t + i * 256;
      int row = f >> 2, ko = (f & 3) * 8;
      int mg = m0 + row;
      uint4 v = make_uint4(0, 0, 0, 0);
      if (mg < SP) v = *(const uint4*)&A[(size_t)mg * DM + k0 + ko];
      *(uint4*)&As[row * LDT + ko] = v;
      uint4 w = *(const uint4*)&Bt[(size_t)(n0 + row) * DM + k0 + ko];
      *(uint4*)&Bs[row * LDT + ko] = w;
    }
    __syncthreads();
    s16x8 af[4], bfr[4];
#pragma unroll
    for (int i = 0; i < 4; i++)
      af[i] = *(const s16x8*)&As[(wm + i * 16 + l15) * LDT + quad * 8];
#pragma unroll
    for (int j = 0; j < 4; j++)
      bfr[j] = *(const s16x8*)&Bs[(wn + j * 16 + l15) * LDT + quad * 8];
#pragma unroll
    for (int i = 0; i < 4; i++)
#pragma unroll
      for (int j = 0; j < 4; j++)
        acc[i][j] = __builtin_amdgcn_mfma_f32_16x16x32_bf16(af[i], bfr[j], acc[i][j], 0, 0, 0);
    __syncthreads();
  }

  ushort* C = Cv + (size_t)bq * SP * DM;
#pragma unroll
  for (int j = 0; j < 4; j++) {
    int n = n0 + wn + j * 16 + l15;
    float bb = bias[n];
#pragma unroll
    for (int i = 0; i < 4; i++) {
      int mb = m0 + wm + i * 16 + quad * 4;
#pragma unroll
      for (int r2 = 0; r2 < 4; r2++) {
        int m = mb + r2;
        if (m < SP) C[(size_t)m * DM + n] = f2b(acc[i][j][r2] + bb);
      }
    }
  }
}

// ---------------------------------------------------------------------------
// Fused ReadUnit GEMM pair (v18, verified R10: LDS alias, 2 blocks/CU,
// glds16 kproj staging)
// ---------------------------------------------------------------------------
__global__ __launch_bounds__(512, 4) void k_fused12(
    const ushort* __restrict__ kproj, const ushort* __restrict__ befft,
    const ushort* __restrict__ wc2t, const float* __restrict__ bcat,
    const float* __restrict__ bcat2, const float* __restrict__ cbuf,
    const float* __restrict__ raw, float* __restrict__ rl)
{
  extern __shared__ __align__(16) char smem[];
  ushort* Af  = (ushort*)smem;                 // 64*520 (kproj tile, then Il)
  float*  red = (float*)(Af + 64 * ILS);       // 64*8

  const int tile = blockIdx.x;                 // 0..799
  const int g = tile & 7, r = tile >> 3;       // r in 0..99
  const int b  = g * 4 + (r / 25);
  const int m0 = (r % 25) * 64;
  const int t  = threadIdx.x;
  const int lane = t & 63, w = t >> 6;         // 8 waves
  const int l15 = lane & 15, quad = lane >> 4;

  const ushort* kpb = kproj + (size_t)b * SP * DM;
#pragma unroll
  for (int i = 0; i < 8; i++) {
    int row = w * 8 + i;                       // wave-uniform
    int mg = m0 + row;
    if (mg >= SP) mg = SP - 1;                 // clamp (outputs masked later)
    glds16(&Af[row * ILS], &kpb[(size_t)mg * DM + lane * 8]);
  }
  __syncthreads();   // drains vmcnt(0)

  // ---- stage A: each wave covers n1 = w*64 .. w*64+63 ----
  const ushort* bfb = befft + (size_t)b * DM * DM;
  f32x4 acc[4][4];
#pragma unroll
  for (int i = 0; i < 4; i++)
#pragma unroll
    for (int j = 0; j < 4; j++) acc[i][j] = (f32x4){0.f, 0.f, 0.f, 0.f};
#pragma unroll 2
  for (int k0 = 0; k0 < DM; k0 += 32) {
    s16x8 bf[4], af[4];
#pragma unroll
    for (int j = 0; j < 4; j++)
      bf[j] = *(const s16x8*)&bfb[(size_t)(w * 64 + j * 16 + l15) * DM + k0 + quad * 8];
#pragma unroll
    for (int i = 0; i < 4; i++)
      af[i] = *(const s16x8*)&Af[(i * 16 + l15) * ILS + k0 + quad * 8];
#pragma unroll
    for (int i = 0; i < 4; i++)
#pragma unroll
      for (int j = 0; j < 4; j++)
        acc[i][j] = __builtin_amdgcn_mfma_f32_16x16x32_bf16(af[i], bf[j], acc[i][j], 0, 0, 0);
  }
  __syncthreads();   // all Af reads complete before Il overwrites it

#pragma unroll
  for (int j = 0; j < 4; j++) {
    int n1 = w * 64 + j * 16 + l15;
    float bc = bcat[n1];
#pragma unroll
    for (int i = 0; i < 4; i++)
#pragma unroll
      for (int r2 = 0; r2 < 4; r2++)
        Af[(i * 16 + quad * 4 + r2) * ILS + n1] = f2b(eluf(acc[i][j][r2] + bc));
  }
  __syncthreads();

  // ---- stage B: each wave covers n2 = w*64 .. w*64+63 ----
  f32x4 acc2[4][4];
#pragma unroll
  for (int i = 0; i < 4; i++)
#pragma unroll
    for (int j = 0; j < 4; j++) acc2[i][j] = (f32x4){0.f, 0.f, 0.f, 0.f};
#pragma unroll 2
  for (int kk = 0; kk < DM; kk += 32) {
    s16x8 af[4], bf[4];
#pragma unroll
    for (int i = 0; i < 4; i++)
      af[i] = *(const s16x8*)&Af[(i * 16 + l15) * ILS + kk + quad * 8];
#pragma unroll
    for (int j = 0; j < 4; j++)
      bf[j] = *(const s16x8*)&wc2t[(size_t)(w * 64 + j * 16 + l15) * DM + kk + quad * 8];
#pragma unroll
    for (int i = 0; i < 4; i++)
#pragma unroll
      for (int j = 0; j < 4; j++)
        acc2[i][j] = __builtin_amdgcn_mfma_f32_16x16x32_bf16(af[i], bf[j], acc2[i][j], 0, 0, 0);
  }

  // ---- epilogue: rl[m] = sum_n elu((acc2 + bcat2)*c)*raw ----
  float epi[16];
#pragma unroll
  for (int e = 0; e < 16; e++) epi[e] = 0.f;
#pragma unroll
  for (int j = 0; j < 4; j++) {
    int n2 = w * 64 + j * 16 + l15;
    float b2 = bcat2[n2], cc = cbuf[(size_t)b * DM + n2], rw = raw[n2];
#pragma unroll
    for (int i = 0; i < 4; i++)
#pragma unroll
      for (int r2 = 0; r2 < 4; r2++)
        epi[i * 4 + r2] += eluf((acc2[i][j][r2] + b2) * cc) * rw;
  }
#pragma unroll
  for (int d2 = 1; d2 < 16; d2 <<= 1)
#pragma unroll
    for (int e = 0; e < 16; e++) epi[e] += __shfl_xor(epi[e], d2, 64);
  if (l15 == 0) {
#pragma unroll
    for (int i = 0; i < 4; i++)
#pragma unroll
      for (int r2 = 0; r2 < 4; r2++)
        red[(i * 16 + quad * 4 + r2) * 8 + w] = epi[i * 4 + r2];
  }
  __syncthreads();
  if (t < 64) {
    int m = m0 + t;
    if (m < SP) {
      float s = 0.f;
#pragma unroll
      for (int q = 0; q < 8; q++) s += red[t * 8 + q];
      rl[(size_t)b * SP + m] = s;
    }
  }
}

// ---------------------------------------------------------------------------
// Per-step fold: befft[b][n][k] = bf16(mp[b][k]*Wcat[k][n] + Wcat[512+k][n])
// (fp32 Wcat — R9 constraint)
// ---------------------------------------------------------------------------
__global__ __launch_bounds__(256) void k_prefold(
    const float* __restrict__ Wcat, const float* __restrict__ mp,
    ushort* __restrict__ Bf)
{
  const int k0 = blockIdx.x * 64, n0 = blockIdx.y * 64;
  const int bbase = blockIdx.z * 8;
  __shared__ float S1[64][68], S2[64][68];
  const int t = threadIdx.x;
#pragma unroll
  for (int i = 0; i < 4; i++) {
    int f = t + i * 256;
    int kk = f >> 4, nn2 = (f & 15) * 4;
    float4 a = *(const float4*)&Wcat[(size_t)(k0 + kk) * DM + n0 + nn2];
    float4 c = *(const float4*)&Wcat[(size_t)(DM + k0 + kk) * DM + n0 + nn2];
    *(float4*)&S1[kk][nn2] = a;
    *(float4*)&S2[kk][nn2] = c;
  }
  __syncthreads();
  const int n = t >> 2, kseg = (t & 3) * 16;
  for (int bq = 0; bq < 8; bq++) {
    const float* mpb = mp + (size_t)(bbase + bq) * DM + k0 + kseg;
    ushort* out = Bf + ((size_t)(bbase + bq) * DM + n0 + n) * DM + k0 + kseg;
#pragma unroll
    for (int g = 0; g < 4; g++) {
      ushort4 o;
      o.x = f2b(mpb[g * 4 + 0] * S1[kseg + g * 4 + 0][n] + S2[kseg + g * 4 + 0][n]);
      o.y = f2b(mpb[g * 4 + 1] * S1[kseg + g * 4 + 1][n] + S2[kseg + g * 4 + 1][n]);
      o.z = f2b(mpb[g * 4 + 2] * S1[kseg + g * 4 + 2][n] + S2[kseg + g * 4 + 2][n]);
      o.w = f2b(mpb[g * 4 + 3] * S1[kseg + g * 4 + 3][n] + S2[kseg + g * 4 + 3][n]);
      *(ushort4*)&out[g * 4] = o;
    }
  }
}

// ---------------------------------------------------------------------------
// Control unit (R5/R8-measured version — fp32 weights, 512 threads)
// ---------------------------------------------------------------------------
__global__ __launch_bounds__(512) void k_ctrl(
    const float* cin, const float* __restrict__ min_,
    const float* __restrict__ Wci, const float* __restrict__ bci,
    const float* __restrict__ Wu_i, const float* __restrict__ bu_i,
    const float* __restrict__ caw, const float* __restrict__ concepts,
    const float* __restrict__ Wm, const float* __restrict__ bm,
    float* cout, float* __restrict__ mpout)
{
  const int b = blockIdx.x, t = threadIdx.x;   // 512 threads
  __shared__ float sc[512], sm[512], sq0[512], sqa[512], scl[80], red[512];
  sc[t] = cin[b * DM + t];
  sm[t] = min_[b * DM + t];
  __syncthreads();
  {
    const int d = t;
    float a0 = bci[d], a1 = 0.f, a2 = 0.f, a3 = 0.f;
    for (int k = 0; k < 512; k += 4) {
      a0 = fmaf(sc[k + 0], Wci[(size_t)(k + 0) * DM + d], a0);
      a1 = fmaf(sc[k + 1], Wci[(size_t)(k + 1) * DM + d], a1);
      a2 = fmaf(sc[k + 2], Wci[(size_t)(k + 2) * DM + d], a2);
      a3 = fmaf(sc[k + 3], Wci[(size_t)(k + 3) * DM + d], a3);
    }
    for (int k = 0; k < 512; k += 4) {
      a0 = fmaf(sm[k + 0], Wci[(size_t)(512 + k + 0) * DM + d], a0);
      a1 = fmaf(sm[k + 1], Wci[(size_t)(512 + k + 1) * DM + d], a1);
      a2 = fmaf(sm[k + 2], Wci[(size_t)(512 + k + 2) * DM + d], a2);
      a3 = fmaf(sm[k + 3], Wci[(size_t)(512 + k + 3) * DM + d], a3);
    }
    sq0[d] = tanhf((a0 + a1) + (a2 + a3));
    float p0 = bm[d], p1 = 0.f, p2 = 0.f, p3 = 0.f;
    for (int k = 0; k < 512; k += 4) {
      p0 = fmaf(sm[k + 0], Wm[(size_t)(k + 0) * DM + d], p0);
      p1 = fmaf(sm[k + 1], Wm[(size_t)(k + 1) * DM + d], p1);
      p2 = fmaf(sm[k + 2], Wm[(size_t)(k + 2) * DM + d], p2);
      p3 = fmaf(sm[k + 3], Wm[(size_t)(k + 3) * DM + d], p3);
    }
    mpout[b * DM + d] = (p0 + p1) + (p2 + p3);
  }
  __syncthreads();
  {
    const int d = t;
    float a0 = bu_i[d], a1 = 0.f, a2 = 0.f, a3 = 0.f;
    for (int k = 0; k < 512; k += 4) {
      a0 = fmaf(sq0[k + 0], Wu_i[(size_t)(k + 0) * DM + d], a0);
      a1 = fmaf(sq0[k + 1], Wu_i[(size_t)(k + 1) * DM + d], a1);
      a2 = fmaf(sq0[k + 2], Wu_i[(size_t)(k + 2) * DM + d], a2);
      a3 = fmaf(sq0[k + 3], Wu_i[(size_t)(k + 3) * DM + d], a3);
    }
    sqa[d] = ((a0 + a1) + (a2 + a3)) * caw[d];
  }
  __syncthreads();
  float myl = -INFINITY;
  if (t < 80) {
    float a0 = 0.f, a1 = 0.f, a2 = 0.f, a3 = 0.f;
    for (int d = 0; d < 512; d += 4) {
      a0 = fmaf(sqa[d + 0], concepts[(size_t)t * DM + d + 0], a0);
      a1 = fmaf(sqa[d + 1], concepts[(size_t)t * DM + d + 1], a1);
      a2 = fmaf(sqa[d + 2], concepts[(size_t)t * DM + d + 2], a2);
      a3 = fmaf(sqa[d + 3], concepts[(size_t)t * DM + d + 3], a3);
    }
    float a = (a0 + a1) + (a2 + a3);
    scl[t] = a; myl = a;
  }
  red[t] = myl; __syncthreads();
  for (int s = 256; s > 0; s >>= 1) { if (t < s) red[t] = fmaxf(red[t], red[t + s]); __syncthreads(); }
  float mx = red[0]; __syncthreads();
  float e = 0.f;
  if (t < 80) e = expf(scl[t] - mx);
  red[t] = e; __syncthreads();
  for (int s = 256; s > 0; s >>= 1) { if (t < s) red[t] += red[t + s]; __syncthreads(); }
  float inv = 1.f / red[0]; __syncthreads();
  if (t < 80) scl[t] = e * inv;
  __syncthreads();
  {
    const int d = t;
    float a0 = 0.f, a1 = 0.f, a2 = 0.f, a3 = 0.f;
    for (int l = 0; l < 80; l += 4) {
      a0 = fmaf(scl[l + 0], concepts[(size_t)(l + 0) * DM + d], a0);
      a1 = fmaf(scl[l + 1], concepts[(size_t)(l + 1) * DM + d], a1);
      a2 = fmaf(scl[l + 2], concepts[(size_t)(l + 2) * DM + d], a2);
      a3 = fmaf(scl[l + 3], concepts[(size_t)(l + 3) * DM + d], a3);
    }
    cout[b * DM + d] = (a0 + a1) + (a2 + a3);
  }
}

// ---------------------------------------------------------------------------
// Fused read softmax + info partial (unchanged, NCH=32)
// ---------------------------------------------------------------------------
__global__ __launch_bounds__(256) void k_softinfo(
    const float* __restrict__ rl, const ushort* __restrict__ know,
    float* __restrict__ ipart)
{
  const int b = blockIdx.x, c = blockIdx.y, t = threadIdx.x;  // c in 0..31
  __shared__ float red[256];
  __shared__ float rprob[49];
  float vals[7]; float vmax = -INFINITY;
#pragma unroll
  for (int q = 0; q < 7; q++) {
    int s = t + q * 256;
    float v = (s < SP) ? rl[(size_t)b * SP + s] : -INFINITY;
    vals[q] = v; vmax = fmaxf(vmax, v);
  }
  red[t] = vmax; __syncthreads();
  for (int s = 128; s > 0; s >>= 1) { if (t < s) red[t] = fmaxf(red[t], red[t + s]); __syncthreads(); }
  float mx = red[0]; __syncthreads();
  float lsum = 0.f;
#pragma unroll
  for (int q = 0; q < 7; q++) {
    int s = t + q * 256;
    lsum += (s < SP) ? expf(vals[q] - mx) : 0.f;
  }
  red[t] = lsum; __syncthreads();
  for (int s = 128; s > 0; s >>= 1) { if (t < s) red[t] += red[t + s]; __syncthreads(); }
  float inv = 1.f / red[0];

  if (t < 49) rprob[t] = expf(rl[(size_t)b * SP + c * 49 + t] - mx) * inv;
  __syncthreads();

  float a0 = 0.f, a1 = 0.f;
  const ushort* kb = know + (size_t)b * SP * DM + (size_t)c * 49 * DM + 2 * t;
  for (int si = 0; si < 49; si++) {
    float r = rprob[si];
    ushort2 kv = *(const ushort2*)&kb[(size_t)si * DM];
    a0 = fmaf(r, b2f(kv.x), a0);
    a1 = fmaf(r, b2f(kv.y), a1);
  }
  ipart[((size_t)b * NCH + c) * DM + 2 * t] = a0;
  ipart[((size_t)b * NCH + c) * DM + 2 * t + 1] = a1;
}

// m_new = [m_old, info] @ Wwrite + bwrite (fp32 weights — R9 constraint)
__global__ __launch_bounds__(256) void k_write(
    const float* __restrict__ mold, const float* __restrict__ ipart,
    const float* __restrict__ Ww, const float* __restrict__ bw,
    float* __restrict__ mnew)
{
  const int b = blockIdx.x, half = blockIdx.y, t = threadIdx.x;
  __shared__ float smo[512], sinfo[512];
  for (int k = t; k < 512; k += 256) {
    smo[k] = mold[b * DM + k];
    float s0 = 0.f, s1 = 0.f, s2 = 0.f, s3 = 0.f;
    for (int c = 0; c < NCH; c += 4) {
      s0 += ipart[((size_t)b * NCH + c + 0) * DM + k];
      s1 += ipart[((size_t)b * NCH + c + 1) * DM + k];
      s2 += ipart[((size_t)b * NCH + c + 2) * DM + k];
      s3 += ipart[((size_t)b * NCH + c + 3) * DM + k];
    }
    sinfo[k] = (s0 + s1) + (s2 + s3);
  }
  __syncthreads();
  int d = half * 256 + t;
  float a0 = bw[d], a1 = 0.f, a2 = 0.f, a3 = 0.f;
  for (int k = 0; k < 512; k += 4) {
    a0 = fmaf(smo[k + 0], Ww[(size_t)(k + 0) * DM + d], a0);
    a1 = fmaf(smo[k + 1], Ww[(size_t)(k + 1) * DM + d], a1);
    a2 = fmaf(smo[k + 2], Ww[(size_t)(k + 2) * DM + d], a2);
    a3 = fmaf(smo[k + 3], Ww[(size_t)(k + 3) * DM + d], a3);
  }
  for (int k = 0; k < 512; k += 4) {
    a0 = fmaf(sinfo[k + 0], Ww[(size_t)(512 + k + 0) * DM + d], a0);
    a1 = fmaf(sinfo[k + 1], Ww[(size_t)(512 + k + 1) * DM + d], a1);
    a2 = fmaf(sinfo[k + 2], Ww[(size_t)(512 + k + 2) * DM + d], a2);
    a3 = fmaf(sinfo[k + 3], Ww[(size_t)(512 + k + 3) * DM + d], a3);
  }
  mnew[b * DM + d] = (a0 + a1) + (a2 + a3);
}

__global__ void k_init(const float* __restrict__ initc, const float* __restrict__ initm,
                       float* __restrict__ cbuf, float* __restrict__ mbuf)
{
  const int b = blockIdx.x, t = threadIdx.x;
  cbuf[b * DM + t] = initc[t];
  mbuf[b * DM + t] = initm[t];
}

__global__ void k_mpo(const float* __restrict__ m, const float* __restrict__ Wproj,
                      const float* __restrict__ bproj, const float* __restrict__ ow,
                      float* __restrict__ mw)
{
  const int b = blockIdx.x, t = threadIdx.x;
  __shared__ float smem[512];
  for (int k = t; k < 512; k += 320) smem[k] = m[b * DM + k];
  __syncthreads();
  if (t < 300) {
    float a0 = bproj[t], a1 = 0.f, a2 = 0.f, a3 = 0.f;
    for (int k = 0; k < 512; k += 4) {
      a0 = fmaf(smem[k + 0], Wproj[(size_t)(k + 0) * 300 + t], a0);
      a1 = fmaf(smem[k + 1], Wproj[(size_t)(k + 1) * 300 + t], a1);
      a2 = fmaf(smem[k + 2], Wproj[(size_t)(k + 2) * 300 + t], a2);
      a3 = fmaf(smem[k + 3], Wproj[(size_t)(k + 3) * 300 + t], a3);
    }
    mw[b * 300 + t] = ((a0 + a1) + (a2 + a3)) * ow[t];
  }
}

__global__ void k_logits(const float* __restrict__ mw, const float* __restrict__ labels,
                         float* __restrict__ logits)
{
  const int b = blockIdx.x, t = threadIdx.x;
  const int a = blockIdx.y * 256 + t;
  __shared__ float smw[300];
  for (int p = t; p < 300; p += 256) smw[p] = mw[b * 300 + p];
  __syncthreads();
  if (a < 1000) {
    float a0 = 0.f, a1 = 0.f, a2 = 0.f, a3 = 0.f;
    for (int p = 0; p < 300; p += 4) {
      a0 = fmaf(smw[p + 0], labels[(size_t)a * 300 + p + 0], a0);
      a1 = fmaf(smw[p + 1], labels[(size_t)a * 300 + p + 1], a1);
      a2 = fmaf(smw[p + 2], labels[(size_t)a * 300 + p + 2], a2);
      a3 = fmaf(smw[p + 3], labels[(size_t)a * 300 + p + 3], a3);
    }
    logits[b * 1000 + a] = (a0 + a1) + (a2 + a3);
  }
}

__global__ void k_softmax_out(const float* __restrict__ logits, float* __restrict__ out)
{
  const int b = blockIdx.x, t = threadIdx.x;
  __shared__ float red[256];
  float v[4]; float vmax = -INFINITY;
#pragma unroll
  for (int q = 0; q < 4; q++) {
    int a = t + q * 256;
    v[q] = (a < 1000) ? logits[b * 1000 + a] : -INFINITY;
    vmax = fmaxf(vmax, v[q]);
  }
  red[t] = vmax; __syncthreads();
  for (int s = 128; s > 0; s >>= 1) { if (t < s) red[t] = fmaxf(red[t], red[t + s]); __syncthreads(); }
  float mx = red[0]; __syncthreads();
  float lsum = 0.f;
#pragma unroll
  for (int q = 0; q < 4; q++) {
    int a = t + q * 256;
    v[q] = (a < 1000) ? expf(v[q] - mx) : 0.f;
    lsum += v[q];
  }
  red[t] = lsum; __syncthreads();
  for (int s = 128; s > 0; s >>= 1) { if (t < s) red[t] += red[t + s]; __syncthreads(); }
  float inv = 1.f / red[0];
#pragma unroll
  for (int q = 0; q < 4; q++) {
    int a = t + q * 256;
    if (a < 1000) out[b * 1000 + a] = v[q] * inv;
  }
}

// ---------------------------------------------------------------------------
extern "C" void kernel_launch(void* const* d_in, const int* in_sizes, int n_in,
                              void* d_out, int out_size, void* d_ws, size_t ws_size,
                              hipStream_t stream)
{
  const float* image    = (const float*)d_in[0];
  const float* concepts = (const float*)d_in[1];
  const float* conv1_w  = (const float*)d_in[2];
  const float* conv1_b  = (const float*)d_in[3];
  const float* conv2_w  = (const float*)d_in[4];
  const float* conv2_b  = (const float*)d_in[5];
  const float* Wci      = (const float*)d_in[6];
  const float* bci      = (const float*)d_in[7];
  const float* Wu       = (const float*)d_in[8];
  const float* bu       = (const float*)d_in[9];
  const float* caw      = (const float*)d_in[10];
  const float* Wk       = (const float*)d_in[12];
  const float* bk       = (const float*)d_in[13];
  const float* Wm       = (const float*)d_in[14];
  const float* bm       = (const float*)d_in[15];
  const float* Wcat     = (const float*)d_in[16];
  const float* bcat     = (const float*)d_in[17];
  const float* Wcat2    = (const float*)d_in[18];
  const float* bcat2    = (const float*)d_in[19];
  const float* raw      = (const float*)d_in[20];
  const float* Wwrite   = (const float*)d_in[22];
  const float* bwrite   = (const float*)d_in[23];
  const float* initc    = (const float*)d_in[24];
  const float* initm    = (const float*)d_in[25];
  const float* Wproj    = (const float*)d_in[26];
  const float* bproj    = (const float*)d_in[27];
  const float* oaw      = (const float*)d_in[28];
  const float* labels   = (const float*)d_in[30];

  char* ws = (char*)d_ws;
  const size_t OFF_KNOW = 0;
  const size_t OFF_XPAD = 51380224;
  const size_t SZ_XPAD  = 83951616;
  const size_t OFF_W    = OFF_XPAD + SZ_XPAD;
  const size_t OFF_WKT  = OFF_W + 14155776;
  const size_t OFF_WC2T = OFF_WKT + 524288;
  size_t off = OFF_WC2T + 524288;
  auto allocB = [&](size_t bytes) {
    void* p = ws + off; off += (bytes + 255) & ~(size_t)255; return p;
  };
  ushort* know   = (ushort*)(ws + OFF_KNOW);
  ushort* imgpad = (ushort*)(ws + OFF_KNOW);                 // stem only
  ushort* xpad1  = (ushort*)(ws + OFF_XPAD);                 // stem only
  ushort* kproj  = (ushort*)(ws + OFF_XPAD);                 // loop
  ushort* befft  = (ushort*)(ws + OFF_XPAD + 51380224);      // loop, 16.78MB
  float*  rl     = (float*) (ws + OFF_XPAD + 68157440);      // loop, 0.2MB
  ushort* w1b    = (ushort*)(ws + OFF_W);
  ushort* w2b    = (ushort*)(ws + OFF_W);
  ushort* wkt    = (ushort*)(ws + OFF_WKT);
  ushort* wc2t   = (ushort*)(ws + OFF_WC2T);
  float* ipart  = (float*)allocB((size_t)BATCH * NCH * DM * 4);
  float* cbuf   = (float*)allocB(BATCH * DM * 4);
  float* mbufA  = (float*)allocB(BATCH * DM * 4);
  float* mbufB  = (float*)allocB(BATCH * DM * 4);
  float* mp     = (float*)allocB(BATCH * DM * 4);
  float* mw     = (float*)allocB(BATCH * 300 * 4);
  float* logits = (float*)allocB(BATCH * 1000 * 4);
  if (off > ws_size) return;  // graceful fail

  const int FUSED_LDS = 64 * ILS * 2 + 64 * 8 * 4;  // 68,608 B -> 2 blocks/CU
  hipFuncSetAttribute((const void*)k_fused12,
                      hipFuncAttributeMaxDynamicSharedMemorySize, FUSED_LDS);

  // --- stem ---
  k_zero<<<4096, 256, 0, stream>>>((uint4*)imgpad, 2625536L);
  k_zero<<<4096, 256, 0, stream>>>((uint4*)xpad1, 5246976L);
  k_padimg<<<dim3(BATCH, 49), 256, 0, stream>>>(image, imgpad);
  k_cvtw<256><<<512, 256, 0, stream>>>(conv1_w, w1b);
  k_cvtT<<<1024, 256, 0, stream>>>(Wk, wkt);
  k_cvtT<<<1024, 256, 0, stream>>>(Wcat2, wc2t);
  k_convm<256, 1><<<1664, 256, 0, stream>>>(w1b, imgpad, conv1_b, xpad1);
  k_cvtw<512><<<512, 256, 0, stream>>>(conv2_w, w2b);
  k_convm<512, 0><<<1664, 256, 0, stream>>>(w2b, xpad1, conv2_b, know);
  k_gemmm<<<1664, 256, 0, stream>>>(know, wkt, bk, kproj);
  k_init<<<BATCH, DM, 0, stream>>>(initc, initm, cbuf, mbufA);

  float* mc = mbufA; float* mn = mbufB;
  for (int i = 0; i < NSTEP; i++) {
    k_ctrl<<<BATCH, 512, 0, stream>>>(cbuf, mc, Wci, bci,
                                      Wu + (size_t)i * DM * DM, bu + i * DM,
                                      caw, concepts, Wm, bm, cbuf, mp);
    k_prefold<<<dim3(8, 8, 4), 256, 0, stream>>>(Wcat, mp, befft);
    k_fused12<<<dim3(800), 512, FUSED_LDS, stream>>>(
        kproj, befft, wc2t, bcat, bcat2, cbuf, raw, rl);
    k_softinfo<<<dim3(BATCH, NCH), 256, 0, stream>>>(rl, know, ipart);
    k_write<<<dim3(BATCH, 2), 256, 0, stream>>>(mc, ipart, Wwrite, bwrite, mn);
    float* tswap = mc; mc = mn; mn = tswap;
  }

  k_mpo<<<BATCH, 320, 0, stream>>>(mc, Wproj, bproj, oaw, mw);
  k_logits<<<dim3(BATCH, 4), 256, 0, stream>>>(mw, labels, logits);
  k_softmax_out<<<BATCH, 256, 0, stream>>>(logits, (float*)d_out);

  (void)in_sizes; (void)n_in; (void)out_size;
}

// Round 12
// 4498.263 us; speedup vs baseline: 1.0569x; 1.0099x over previous
//
#include <hip/hip_runtime.h>
#include <math.h>

#define DM    512
#define SP    1568   // 8*14*14
#define BATCH 32
#define NSTEP 12
#define CPAD  2560   // padded per-batch spatial rows (10*16*16)
#define LDT   40     // kproj-GEMM LDS row stride (bf16)
#define ILS   520    // fused kernel LDS row stride (bf16)
#define NCH   32     // softinfo chunks: 49 rows each

typedef short s16x8 __attribute__((ext_vector_type(8)));
typedef float f32x4 __attribute__((ext_vector_type(4)));

__device__ __forceinline__ float eluf(float x) { return x > 0.f ? x : expf(x) - 1.f; }
__device__ __forceinline__ float b2f(ushort u) {
  union { float f; unsigned i; } v; v.i = ((unsigned)u) << 16; return v.f;
}
__device__ __forceinline__ ushort f2b(float f) {
  union { float f; unsigned i; } v; v.f = f;
  unsigned r = (v.i + 0x7FFFu + ((v.i >> 16) & 1u)) >> 16;
  return (ushort)r;
}

// async global->LDS, 16B per lane; LDS dest must be wave-uniform base
// (lanes land at base + lane*16B); global src is per-lane.
__device__ __forceinline__ void glds16(ushort* l, const ushort* g) {
  __builtin_amdgcn_global_load_lds(
      (const __attribute__((address_space(1))) void*)g,
      (__attribute__((address_space(3))) void*)l, 16, 0, 0);
}

// ---------------------------------------------------------------------------
// NUMERICS CONSTRAINT (measured R9): the recurrent-path weights (Wci, Wm,
// Wu, Wwrite, Wcat) must stay fp32 — bf16-quantizing them flipped the
// 12-step attention recurrence (absmax 0.83 vs 0.02 threshold). Only the
// feed-forward bulk tensors (know/kproj/befft/wc2t, conv weights) are bf16.
// ---------------------------------------------------------------------------
__global__ void k_zero(uint4* __restrict__ p, long n16) {
  long stride = (long)gridDim.x * blockDim.x;
  for (long i = (long)blockIdx.x * blockDim.x + threadIdx.x; i < n16; i += stride)
    p[i] = make_uint4(0, 0, 0, 0);
}

// image [32][256][1568] fp32 -> NHWC padded bf16 [b][2560][256] (interior only)
__global__ __launch_bounds__(256) void k_padimg(const float* __restrict__ img,
                                               ushort* __restrict__ xp) {
  const int b = blockIdx.x, s0 = blockIdx.y * 32;   // grid (32, 49)
  __shared__ float T[256][33];
  const int t = threadIdx.x;
  const int so = t & 31, cg = t >> 5;               // 8 ci-groups of 32
#pragma unroll 4
  for (int i = 0; i < 32; i++) {
    int ci = cg * 32 + i;
    T[ci][so] = img[((size_t)(b * 256 + ci)) * SP + s0 + so];
  }
  __syncthreads();
#pragma unroll 4
  for (int si = 0; si < 32; si++) {
    int s = s0 + si;
    int z = s / 196, r = s - z * 196, y = r / 14, x = r - y * 14;
    int p = (z + 1) * 256 + (y + 1) * 16 + (x + 1);
    xp[((size_t)b * CPAD + p) * 256 + t] = f2b(T[t][si]);
  }
}

// conv weights [co][ci][27] fp32 -> tap-major bf16 [co][tap*CIN+ci]
template <int CIN>
__global__ __launch_bounds__(256) void k_cvtw(const float* __restrict__ w,
                                              ushort* __restrict__ o) {
  const int co = blockIdx.x;           // 512 blocks
  const int KK = 27 * CIN;
  __shared__ ushort tmp[27 * CIN];
  const int t = threadIdx.x;
  for (int i = t; i < KK; i += 256)
    tmp[i] = f2b(w[(size_t)co * KK + i]);      // src linear: i = ci*27+tap
  __syncthreads();
  for (int i = t; i < KK; i += 256) {
    int tap = i / CIN, ci = i - tap * CIN;     // dst linear: i = tap*CIN+ci
    o[(size_t)co * KK + i] = tmp[ci * 27 + tap];
  }
}

// [512][512] fp32 -> transposed bf16 [n][k]
__global__ void k_cvtT(const float* __restrict__ w, ushort* __restrict__ o) {
  int idx = blockIdx.x * 256 + threadIdx.x;   // < 512*512
  int n = idx >> 9, k = idx & 511;
  o[idx] = f2b(w[(size_t)k * 512 + n]);
}

// ---------------------------------------------------------------------------
// MFMA conv3d v20 — v19 (tap-outer, hoisted addresses) + T5 s_setprio
// around the MFMA cluster. With 2 blocks/CU at unsynchronized barrier
// phases, boosting MFMA-issuing waves keeps the matrix pipe fed while the
// other block drains vmcnt at its barrier (m191 mechanism; m190's null was
// single-block lockstep).
// ---------------------------------------------------------------------------
template <int CIN, int ISCONV1>
__global__ __launch_bounds__(256) void k_convm(
    const ushort* __restrict__ W, const ushort* __restrict__ Xp,
    const float* __restrict__ bias, ushort* __restrict__ Y)
{
  const int KK = CIN * 27;
  const int id = blockIdx.x;            // 0..1663
  const int g = id & 7, r = id >> 3;    // 8 XCD groups x 208
  const int b  = g * 4 + (r / 52);
  const int rr = r % 52;
  const int m0 = (rr / 13) * 128;
  const int n0 = (rr % 13) * 128;
  __shared__ __align__(16) ushort As[128 * 64];
  __shared__ __align__(16) ushort Bs[128 * 64];
  const int t = threadIdx.x;
  const int lane = t & 63, wid = t >> 6;
  const int wm = (wid >> 1) * 64, wn = (wid & 1) * 64;
  const int l15 = lane & 15, quad = lane >> 4;
  const int wrow = lane >> 3, wslot = lane & 7;  // staging row/slot in wave

  // per-thread staging rows and running source pointers (fixed per block)
  const ushort* ap[4];   // A: weights, advance by CIN per tap
  const ushort* bp[4];   // B: activations, advance by tofs*CIN per tap
  ushort* alds[4]; ushort* blds[4];
#pragma unroll
  for (int i = 0; i < 4; i++) {
    int row = wid * 32 + i * 8 + wrow;       // 0..127 within tile
    int gco = (wslot ^ (row & 7)) * 8;       // inverse-swizzled chunk offset
    int n = n0 + row;
    if (n >= SP) n = SP - 1;                 // clamp: outputs there never written
    int z = n / 196, rm = n - z * 196, y = rm / 14, x = rm - y * 14;
    int padrow = z * 256 + y * 16 + x;       // window-start index in padded space
    ap[i] = W + (size_t)(m0 + row) * KK + gco;
    bp[i] = Xp + (size_t)b * CPAD * CIN + (size_t)padrow * CIN + gco;
    alds[i] = &As[(wid * 32 + i * 8) * 64];
    blds[i] = &Bs[(wid * 32 + i * 8) * 64];
  }

  f32x4 acc[4][4];
#pragma unroll
  for (int i = 0; i < 4; i++)
#pragma unroll
    for (int j = 0; j < 4; j++) acc[i][j] = (f32x4){0.f, 0.f, 0.f, 0.f};

  for (int tap = 0; tap < 27; tap++) {
    int dz = tap / 9, rr2 = tap - dz * 9, dy = rr2 / 3, dx = rr2 - dy * 3;
    int toff = (dz * 256 + dy * 16 + dx) * CIN;   // wave-uniform
    int aoff = tap * CIN;
#pragma unroll
    for (int c0 = 0; c0 < CIN; c0 += 64) {
#pragma unroll
      for (int i = 0; i < 4; i++)
        glds16(alds[i], ap[i] + aoff + c0);
#pragma unroll
      for (int i = 0; i < 4; i++)
        glds16(blds[i], bp[i] + toff + c0);
      __syncthreads();   // compiler drains vmcnt(0) before s_barrier
#pragma unroll
      for (int sub = 0; sub < 2; sub++) {
        s16x8 af[4], bfr[4];
#pragma unroll
        for (int i = 0; i < 4; i++) {
          int row = wm + i * 16 + l15;
          int c = sub * 4 + quad;
          af[i] = *(const s16x8*)&As[row * 64 + ((c ^ (row & 7)) * 8)];
        }
#pragma unroll
        for (int j = 0; j < 4; j++) {
          int row = wn + j * 16 + l15;
          int c = sub * 4 + quad;
          bfr[j] = *(const s16x8*)&Bs[row * 64 + ((c ^ (row & 7)) * 8)];
        }
        __builtin_amdgcn_s_setprio(1);
#pragma unroll
        for (int i = 0; i < 4; i++)
#pragma unroll
          for (int j = 0; j < 4; j++)
            acc[i][j] = __builtin_amdgcn_mfma_f32_16x16x32_bf16(af[i], bfr[j], acc[i][j], 0, 0, 0);
        __builtin_amdgcn_s_setprio(0);
      }
      __syncthreads();
    }
  }

  int nout[4]; size_t obase[4];
#pragma unroll
  for (int j = 0; j < 4; j++) {
    int n = n0 + wn + j * 16 + l15;
    nout[j] = n; obase[j] = 0;
    if (n < SP) {
      if (ISCONV1) {
        int z = n / 196, rm = n - z * 196, y = rm / 14, x = rm - y * 14;
        obase[j] = ((size_t)b * CPAD + z * 256 + y * 16 + x + 273) * 512;
      } else {
        obase[j] = ((size_t)b * SP + n) * DM;
      }
    }
  }
#pragma unroll
  for (int i = 0; i < 4; i++) {
    int cob = m0 + wm + i * 16 + quad * 4;
    float4 bb = *(const float4*)&bias[cob];
#pragma unroll
    for (int j = 0; j < 4; j++) {
      if (nout[j] < SP) {
        ushort4 o;
        o.x = f2b(eluf(acc[i][j][0] + bb.x));
        o.y = f2b(eluf(acc[i][j][1] + bb.y));
        o.z = f2b(eluf(acc[i][j][2] + bb.z));
        o.w = f2b(eluf(acc[i][j][3] + bb.w));
        *(ushort4*)&Y[obase[j] + cob] = o;
      }
    }
  }
}

// ---------------------------------------------------------------------------
// MFMA GEMM: kproj = know @ WkT + bk (unchanged, XCD-swizzled)
// ---------------------------------------------------------------------------
__global__ __launch_bounds__(256) void k_gemmm(
    const ushort* __restrict__ A0, const ushort* __restrict__ Bt,
    const float* __restrict__ bias, ushort* __restrict__ Cv)
{
  const int id = blockIdx.x;            // 0..1663
  const int g = id & 7, r = id >> 3;
  const int bq = g * 4 + (r / 52);
  const int rr = r % 52;
  const int n0 = (rr / 13) * 128;
  const int m0 = (rr % 13) * 128;
  const ushort* A = A0 + (size_t)bq * SP * DM;
  __shared__ __align__(16) ushort As[128 * LDT];
  __shared__ __align__(16) ushort Bs[128 * LDT];
  const int t = threadIdx.x;
  const int lane = t & 63, wid = t >> 6;
  const int wm = (wid >> 1) * 64, wn = (wid & 1) * 64;
  const int l15 = lane & 15, quad = lane >> 4;
  f32x4 acc[4][4];
#pragma unroll
  for (int i = 0; i < 4; i++)
#pragma unroll
    for (int j = 0; j < 4; j++) acc[i][j] = (f32x4){0.f, 0.f, 0.f, 0.f};

  for (int k0 = 0; k0 < DM; k0 += 32) {
#pragma unroll
    for (int i = 0; i < 2; i++) {
      int f = t + i * 256;
      int row = f >> 2, ko = (f & 3) * 8;
      int mg = m0 + row;
      uint4 v = make_uint4(0, 0, 0, 0);
      if (mg < SP) v = *(const uint4*)&A[(size_t)mg * DM + k0 + ko];
      *(uint4*)&As[row * LDT + ko] = v;
      uint4 w = *(const uint4*)&Bt[(size_t)(n0 + row) * DM + k0 + ko];
      *(uint4*)&Bs[row * LDT + ko] = w;
    }
    __syncthreads();
    s16x8 af[4], bfr[4];
#pragma unroll
    for (int i = 0; i < 4; i++)
      af[i] = *(const s16x8*)&As[(wm + i * 16 + l15) * LDT + quad * 8];
#pragma unroll
    for (int j = 0; j < 4; j++)
      bfr[j] = *(const s16x8*)&Bs[(wn + j * 16 + l15) * LDT + quad * 8];
#pragma unroll
    for (int i = 0; i < 4; i++)
#pragma unroll
      for (int j = 0; j < 4; j++)
        acc[i][j] = __builtin_amdgcn_mfma_f32_16x16x32_bf16(af[i], bfr[j], acc[i][j], 0, 0, 0);
    __syncthreads();
  }

  ushort* C = Cv + (size_t)bq * SP * DM;
#pragma unroll
  for (int j = 0; j < 4; j++) {
    int n = n0 + wn + j * 16 + l15;
    float bb = bias[n];
#pragma unroll
    for (int i = 0; i < 4; i++) {
      int mb = m0 + wm + i * 16 + quad * 4;
#pragma unroll
      for (int r2 = 0; r2 < 4; r2++) {
        int m = mb + r2;
        if (m < SP) C[(size_t)m * DM + n] = f2b(acc[i][j][r2] + bb);
      }
    }
  }
}

// ---------------------------------------------------------------------------
// Fused ReadUnit GEMM pair v20 — v18 + T5 s_setprio around the MFMA
// clusters (2 blocks/CU at independent phases — m191 mechanism).
// ---------------------------------------------------------------------------
__global__ __launch_bounds__(512, 4) void k_fused12(
    const ushort* __restrict__ kproj, const ushort* __restrict__ befft,
    const ushort* __restrict__ wc2t, const float* __restrict__ bcat,
    const float* __restrict__ bcat2, const float* __restrict__ cbuf,
    const float* __restrict__ raw, float* __restrict__ rl)
{
  extern __shared__ __align__(16) char smem[];
  ushort* Af  = (ushort*)smem;                 // 64*520 (kproj tile, then Il)
  float*  red = (float*)(Af + 64 * ILS);       // 64*8

  const int tile = blockIdx.x;                 // 0..799
  const int g = tile & 7, r = tile >> 3;       // r in 0..99
  const int b  = g * 4 + (r / 25);
  const int m0 = (r % 25) * 64;
  const int t  = threadIdx.x;
  const int lane = t & 63, w = t >> 6;         // 8 waves
  const int l15 = lane & 15, quad = lane >> 4;

  const ushort* kpb = kproj + (size_t)b * SP * DM;
#pragma unroll
  for (int i = 0; i < 8; i++) {
    int row = w * 8 + i;                       // wave-uniform
    int mg = m0 + row;
    if (mg >= SP) mg = SP - 1;                 // clamp (outputs masked later)
    glds16(&Af[row * ILS], &kpb[(size_t)mg * DM + lane * 8]);
  }
  __syncthreads();   // drains vmcnt(0)

  // ---- stage A: each wave covers n1 = w*64 .. w*64+63 ----
  const ushort* bfb = befft + (size_t)b * DM * DM;
  f32x4 acc[4][4];
#pragma unroll
  for (int i = 0; i < 4; i++)
#pragma unroll
    for (int j = 0; j < 4; j++) acc[i][j] = (f32x4){0.f, 0.f, 0.f, 0.f};
#pragma unroll 2
  for (int k0 = 0; k0 < DM; k0 += 32) {
    s16x8 bf[4], af[4];
#pragma unroll
    for (int j = 0; j < 4; j++)
      bf[j] = *(const s16x8*)&bfb[(size_t)(w * 64 + j * 16 + l15) * DM + k0 + quad * 8];
#pragma unroll
    for (int i = 0; i < 4; i++)
      af[i] = *(const s16x8*)&Af[(i * 16 + l15) * ILS + k0 + quad * 8];
    __builtin_amdgcn_s_setprio(1);
#pragma unroll
    for (int i = 0; i < 4; i++)
#pragma unroll
      for (int j = 0; j < 4; j++)
        acc[i][j] = __builtin_amdgcn_mfma_f32_16x16x32_bf16(af[i], bf[j], acc[i][j], 0, 0, 0);
    __builtin_amdgcn_s_setprio(0);
  }
  __syncthreads();   // all Af reads complete before Il overwrites it

#pragma unroll
  for (int j = 0; j < 4; j++) {
    int n1 = w * 64 + j * 16 + l15;
    float bc = bcat[n1];
#pragma unroll
    for (int i = 0; i < 4; i++)
#pragma unroll
      for (int r2 = 0; r2 < 4; r2++)
        Af[(i * 16 + quad * 4 + r2) * ILS + n1] = f2b(eluf(acc[i][j][r2] + bc));
  }
  __syncthreads();

  // ---- stage B: each wave covers n2 = w*64 .. w*64+63 ----
  f32x4 acc2[4][4];
#pragma unroll
  for (int i = 0; i < 4; i++)
#pragma unroll
    for (int j = 0; j < 4; j++) acc2[i][j] = (f32x4){0.f, 0.f, 0.f, 0.f};
#pragma unroll 2
  for (int kk = 0; kk < DM; kk += 32) {
    s16x8 af[4], bf[4];
#pragma unroll
    for (int i = 0; i < 4; i++)
      af[i] = *(const s16x8*)&Af[(i * 16 + l15) * ILS + kk + quad * 8];
#pragma unroll
    for (int j = 0; j < 4; j++)
      bf[j] = *(const s16x8*)&wc2t[(size_t)(w * 64 + j * 16 + l15) * DM + kk + quad * 8];
    __builtin_amdgcn_s_setprio(1);
#pragma unroll
    for (int i = 0; i < 4; i++)
#pragma unroll
      for (int j = 0; j < 4; j++)
        acc2[i][j] = __builtin_amdgcn_mfma_f32_16x16x32_bf16(af[i], bf[j], acc2[i][j], 0, 0, 0);
    __builtin_amdgcn_s_setprio(0);
  }

  // ---- epilogue: rl[m] = sum_n elu((acc2 + bcat2)*c)*raw ----
  float epi[16];
#pragma unroll
  for (int e = 0; e < 16; e++) epi[e] = 0.f;
#pragma unroll
  for (int j = 0; j < 4; j++) {
    int n2 = w * 64 + j * 16 + l15;
    float b2 = bcat2[n2], cc = cbuf[(size_t)b * DM + n2], rw = raw[n2];
#pragma unroll
    for (int i = 0; i < 4; i++)
#pragma unroll
      for (int r2 = 0; r2 < 4; r2++)
        epi[i * 4 + r2] += eluf((acc2[i][j][r2] + b2) * cc) * rw;
  }
#pragma unroll
  for (int d2 = 1; d2 < 16; d2 <<= 1)
#pragma unroll
    for (int e = 0; e < 16; e++) epi[e] += __shfl_xor(epi[e], d2, 64);
  if (l15 == 0) {
#pragma unroll
    for (int i = 0; i < 4; i++)
#pragma unroll
      for (int r2 = 0; r2 < 4; r2++)
        red[(i * 16 + quad * 4 + r2) * 8 + w] = epi[i * 4 + r2];
  }
  __syncthreads();
  if (t < 64) {
    int m = m0 + t;
    if (m < SP) {
      float s = 0.f;
#pragma unroll
      for (int q = 0; q < 8; q++) s += red[t * 8 + q];
      rl[(size_t)b * SP + m] = s;
    }
  }
}

// ---------------------------------------------------------------------------
// Per-step fold: befft[b][n][k] = bf16(mp[b][k]*Wcat[k][n] + Wcat[512+k][n])
// (fp32 Wcat — R9 constraint)
// ---------------------------------------------------------------------------
__global__ __launch_bounds__(256) void k_prefold(
    const float* __restrict__ Wcat, const float* __restrict__ mp,
    ushort* __restrict__ Bf)
{
  const int k0 = blockIdx.x * 64, n0 = blockIdx.y * 64;
  const int bbase = blockIdx.z * 8;
  __shared__ float S1[64][68], S2[64][68];
  const int t = threadIdx.x;
#pragma unroll
  for (int i = 0; i < 4; i++) {
    int f = t + i * 256;
    int kk = f >> 4, nn2 = (f & 15) * 4;
    float4 a = *(const float4*)&Wcat[(size_t)(k0 + kk) * DM + n0 + nn2];
    float4 c = *(const float4*)&Wcat[(size_t)(DM + k0 + kk) * DM + n0 + nn2];
    *(float4*)&S1[kk][nn2] = a;
    *(float4*)&S2[kk][nn2] = c;
  }
  __syncthreads();
  const int n = t >> 2, kseg = (t & 3) * 16;
  for (int bq = 0; bq < 8; bq++) {
    const float* mpb = mp + (size_t)(bbase + bq) * DM + k0 + kseg;
    ushort* out = Bf + ((size_t)(bbase + bq) * DM + n0 + n) * DM + k0 + kseg;
#pragma unroll
    for (int g = 0; g < 4; g++) {
      ushort4 o;
      o.x = f2b(mpb[g * 4 + 0] * S1[kseg + g * 4 + 0][n] + S2[kseg + g * 4 + 0][n]);
      o.y = f2b(mpb[g * 4 + 1] * S1[kseg + g * 4 + 1][n] + S2[kseg + g * 4 + 1][n]);
      o.z = f2b(mpb[g * 4 + 2] * S1[kseg + g * 4 + 2][n] + S2[kseg + g * 4 + 2][n]);
      o.w = f2b(mpb[g * 4 + 3] * S1[kseg + g * 4 + 3][n] + S2[kseg + g * 4 + 3][n]);
      *(ushort4*)&out[g * 4] = o;
    }
  }
}

// ---------------------------------------------------------------------------
// Control unit (R5/R8-measured version — fp32 weights, 512 threads)
// ---------------------------------------------------------------------------
__global__ __launch_bounds__(512) void k_ctrl(
    const float* cin, const float* __restrict__ min_,
    const float* __restrict__ Wci, const float* __restrict__ bci,
    const float* __restrict__ Wu_i, const float* __restrict__ bu_i,
    const float* __restrict__ caw, const float* __restrict__ concepts,
    const float* __restrict__ Wm, const float* __restrict__ bm,
    float* cout, float* __restrict__ mpout)
{
  const int b = blockIdx.x, t = threadIdx.x;   // 512 threads
  __shared__ float sc[512], sm[512], sq0[512], sqa[512], scl[80], red[512];
  sc[t] = cin[b * DM + t];
  sm[t] = min_[b * DM + t];
  __syncthreads();
  {
    const int d = t;
    float a0 = bci[d], a1 = 0.f, a2 = 0.f, a3 = 0.f;
    for (int k = 0; k < 512; k += 4) {
      a0 = fmaf(sc[k + 0], Wci[(size_t)(k + 0) * DM + d], a0);
      a1 = fmaf(sc[k + 1], Wci[(size_t)(k + 1) * DM + d], a1);
      a2 = fmaf(sc[k + 2], Wci[(size_t)(k + 2) * DM + d], a2);
      a3 = fmaf(sc[k + 3], Wci[(size_t)(k + 3) * DM + d], a3);
    }
    for (int k = 0; k < 512; k += 4) {
      a0 = fmaf(sm[k + 0], Wci[(size_t)(512 + k + 0) * DM + d], a0);
      a1 = fmaf(sm[k + 1], Wci[(size_t)(512 + k + 1) * DM + d], a1);
      a2 = fmaf(sm[k + 2], Wci[(size_t)(512 + k + 2) * DM + d], a2);
      a3 = fmaf(sm[k + 3], Wci[(size_t)(512 + k + 3) * DM + d], a3);
    }
    sq0[d] = tanhf((a0 + a1) + (a2 + a3));
    float p0 = bm[d], p1 = 0.f, p2 = 0.f, p3 = 0.f;
    for (int k = 0; k < 512; k += 4) {
      p0 = fmaf(sm[k + 0], Wm[(size_t)(k + 0) * DM + d], p0);
      p1 = fmaf(sm[k + 1], Wm[(size_t)(k + 1) * DM + d], p1);
      p2 = fmaf(sm[k + 2], Wm[(size_t)(k + 2) * DM + d], p2);
      p3 = fmaf(sm[k + 3], Wm[(size_t)(k + 3) * DM + d], p3);
    }
    mpout[b * DM + d] = (p0 + p1) + (p2 + p3);
  }
  __syncthreads();
  {
    const int d = t;
    float a0 = bu_i[d], a1 = 0.f, a2 = 0.f, a3 = 0.f;
    for (int k = 0; k < 512; k += 4) {
      a0 = fmaf(sq0[k + 0], Wu_i[(size_t)(k + 0) * DM + d], a0);
      a1 = fmaf(sq0[k + 1], Wu_i[(size_t)(k + 1) * DM + d], a1);
      a2 = fmaf(sq0[k + 2], Wu_i[(size_t)(k + 2) * DM + d], a2);
      a3 = fmaf(sq0[k + 3], Wu_i[(size_t)(k + 3) * DM + d], a3);
    }
    sqa[d] = ((a0 + a1) + (a2 + a3)) * caw[d];
  }
  __syncthreads();
  float myl = -INFINITY;
  if (t < 80) {
    float a0 = 0.f, a1 = 0.f, a2 = 0.f, a3 = 0.f;
    for (int d = 0; d < 512; d += 4) {
      a0 = fmaf(sqa[d + 0], concepts[(size_t)t * DM + d + 0], a0);
      a1 = fmaf(sqa[d + 1], concepts[(size_t)t * DM + d + 1], a1);
      a2 = fmaf(sqa[d + 2], concepts[(size_t)t * DM + d + 2], a2);
      a3 = fmaf(sqa[d + 3], concepts[(size_t)t * DM + d + 3], a3);
    }
    float a = (a0 + a1) + (a2 + a3);
    scl[t] = a; myl = a;
  }
  red[t] = myl; __syncthreads();
  for (int s = 256; s > 0; s >>= 1) { if (t < s) red[t] = fmaxf(red[t], red[t + s]); __syncthreads(); }
  float mx = red[0]; __syncthreads();
  float e = 0.f;
  if (t < 80) e = expf(scl[t] - mx);
  red[t] = e; __syncthreads();
  for (int s = 256; s > 0; s >>= 1) { if (t < s) red[t] += red[t + s]; __syncthreads(); }
  float inv = 1.f / red[0]; __syncthreads();
  if (t < 80) scl[t] = e * inv;
  __syncthreads();
  {
    const int d = t;
    float a0 = 0.f, a1 = 0.f, a2 = 0.f, a3 = 0.f;
    for (int l = 0; l < 80; l += 4) {
      a0 = fmaf(scl[l + 0], concepts[(size_t)(l + 0) * DM + d], a0);
      a1 = fmaf(scl[l + 1], concepts[(size_t)(l + 1) * DM + d], a1);
      a2 = fmaf(scl[l + 2], concepts[(size_t)(l + 2) * DM + d], a2);
      a3 = fmaf(scl[l + 3], concepts[(size_t)(l + 3) * DM + d], a3);
    }
    cout[b * DM + d] = (a0 + a1) + (a2 + a3);
  }
}

// ---------------------------------------------------------------------------
// Fused read softmax + info partial (unchanged, NCH=32)
// ---------------------------------------------------------------------------
__global__ __launch_bounds__(256) void k_softinfo(
    const float* __restrict__ rl, const ushort* __restrict__ know,
    float* __restrict__ ipart)
{
  const int b = blockIdx.x, c = blockIdx.y, t = threadIdx.x;  // c in 0..31
  __shared__ float red[256];
  __shared__ float rprob[49];
  float vals[7]; float vmax = -INFINITY;
#pragma unroll
  for (int q = 0; q < 7; q++) {
    int s = t + q * 256;
    float v = (s < SP) ? rl[(size_t)b * SP + s] : -INFINITY;
    vals[q] = v; vmax = fmaxf(vmax, v);
  }
  red[t] = vmax; __syncthreads();
  for (int s = 128; s > 0; s >>= 1) { if (t < s) red[t] = fmaxf(red[t], red[t + s]); __syncthreads(); }
  float mx = red[0]; __syncthreads();
  float lsum = 0.f;
#pragma unroll
  for (int q = 0; q < 7; q++) {
    int s = t + q * 256;
    lsum += (s < SP) ? expf(vals[q] - mx) : 0.f;
  }
  red[t] = lsum; __syncthreads();
  for (int s = 128; s > 0; s >>= 1) { if (t < s) red[t] += red[t + s]; __syncthreads(); }
  float inv = 1.f / red[0];

  if (t < 49) rprob[t] = expf(rl[(size_t)b * SP + c * 49 + t] - mx) * inv;
  __syncthreads();

  float a0 = 0.f, a1 = 0.f;
  const ushort* kb = know + (size_t)b * SP * DM + (size_t)c * 49 * DM + 2 * t;
  for (int si = 0; si < 49; si++) {
    float r = rprob[si];
    ushort2 kv = *(const ushort2*)&kb[(size_t)si * DM];
    a0 = fmaf(r, b2f(kv.x), a0);
    a1 = fmaf(r, b2f(kv.y), a1);
  }
  ipart[((size_t)b * NCH + c) * DM + 2 * t] = a0;
  ipart[((size_t)b * NCH + c) * DM + 2 * t + 1] = a1;
}

// m_new = [m_old, info] @ Wwrite + bwrite (fp32 weights — R9 constraint)
__global__ __launch_bounds__(256) void k_write(
    const float* __restrict__ mold, const float* __restrict__ ipart,
    const float* __restrict__ Ww, const float* __restrict__ bw,
    float* __restrict__ mnew)
{
  const int b = blockIdx.x, half = blockIdx.y, t = threadIdx.x;
  __shared__ float smo[512], sinfo[512];
  for (int k = t; k < 512; k += 256) {
    smo[k] = mold[b * DM + k];
    float s0 = 0.f, s1 = 0.f, s2 = 0.f, s3 = 0.f;
    for (int c = 0; c < NCH; c += 4) {
      s0 += ipart[((size_t)b * NCH + c + 0) * DM + k];
      s1 += ipart[((size_t)b * NCH + c + 1) * DM + k];
      s2 += ipart[((size_t)b * NCH + c + 2) * DM + k];
      s3 += ipart[((size_t)b * NCH + c + 3) * DM + k];
    }
    sinfo[k] = (s0 + s1) + (s2 + s3);
  }
  __syncthreads();
  int d = half * 256 + t;
  float a0 = bw[d], a1 = 0.f, a2 = 0.f, a3 = 0.f;
  for (int k = 0; k < 512; k += 4) {
    a0 = fmaf(smo[k + 0], Ww[(size_t)(k + 0) * DM + d], a0);
    a1 = fmaf(smo[k + 1], Ww[(size_t)(k + 1) * DM + d], a1);
    a2 = fmaf(smo[k + 2], Ww[(size_t)(k + 2) * DM + d], a2);
    a3 = fmaf(smo[k + 3], Ww[(size_t)(k + 3) * DM + d], a3);
  }
  for (int k = 0; k < 512; k += 4) {
    a0 = fmaf(sinfo[k + 0], Ww[(size_t)(512 + k + 0) * DM + d], a0);
    a1 = fmaf(sinfo[k + 1], Ww[(size_t)(512 + k + 1) * DM + d], a1);
    a2 = fmaf(sinfo[k + 2], Ww[(size_t)(512 + k + 2) * DM + d], a2);
    a3 = fmaf(sinfo[k + 3], Ww[(size_t)(512 + k + 3) * DM + d], a3);
  }
  mnew[b * DM + d] = (a0 + a1) + (a2 + a3);
}

__global__ void k_init(const float* __restrict__ initc, const float* __restrict__ initm,
                       float* __restrict__ cbuf, float* __restrict__ mbuf)
{
  const int b = blockIdx.x, t = threadIdx.x;
  cbuf[b * DM + t] = initc[t];
  mbuf[b * DM + t] = initm[t];
}

__global__ void k_mpo(const float* __restrict__ m, const float* __restrict__ Wproj,
                      const float* __restrict__ bproj, const float* __restrict__ ow,
                      float* __restrict__ mw)
{
  const int b = blockIdx.x, t = threadIdx.x;
  __shared__ float smem[512];
  for (int k = t; k < 512; k += 320) smem[k] = m[b * DM + k];
  __syncthreads();
  if (t < 300) {
    float a0 = bproj[t], a1 = 0.f, a2 = 0.f, a3 = 0.f;
    for (int k = 0; k < 512; k += 4) {
      a0 = fmaf(smem[k + 0], Wproj[(size_t)(k + 0) * 300 + t], a0);
      a1 = fmaf(smem[k + 1], Wproj[(size_t)(k + 1) * 300 + t], a1);
      a2 = fmaf(smem[k + 2], Wproj[(size_t)(k + 2) * 300 + t], a2);
      a3 = fmaf(smem[k + 3], Wproj[(size_t)(k + 3) * 300 + t], a3);
    }
    mw[b * 300 + t] = ((a0 + a1) + (a2 + a3)) * ow[t];
  }
}

__global__ void k_logits(const float* __restrict__ mw, const float* __restrict__ labels,
                         float* __restrict__ logits)
{
  const int b = blockIdx.x, t = threadIdx.x;
  const int a = blockIdx.y * 256 + t;
  __shared__ float smw[300];
  for (int p = t; p < 300; p += 256) smw[p] = mw[b * 300 + p];
  __syncthreads();
  if (a < 1000) {
    float a0 = 0.f, a1 = 0.f, a2 = 0.f, a3 = 0.f;
    for (int p = 0; p < 300; p += 4) {
      a0 = fmaf(smw[p + 0], labels[(size_t)a * 300 + p + 0], a0);
      a1 = fmaf(smw[p + 1], labels[(size_t)a * 300 + p + 1], a1);
      a2 = fmaf(smw[p + 2], labels[(size_t)a * 300 + p + 2], a2);
      a3 = fmaf(smw[p + 3], labels[(size_t)a * 300 + p + 3], a3);
    }
    logits[b * 1000 + a] = (a0 + a1) + (a2 + a3);
  }
}

__global__ void k_softmax_out(const float* __restrict__ logits, float* __restrict__ out)
{
  const int b = blockIdx.x, t = threadIdx.x;
  __shared__ float red[256];
  float v[4]; float vmax = -INFINITY;
#pragma unroll
  for (int q = 0; q < 4; q++) {
    int a = t + q * 256;
    v[q] = (a < 1000) ? logits[b * 1000 + a] : -INFINITY;
    vmax = fmaxf(vmax, v[q]);
  }
  red[t] = vmax; __syncthreads();
  for (int s = 128; s > 0; s >>= 1) { if (t < s) red[t] = fmaxf(red[t], red[t + s]); __syncthreads(); }
  float mx = red[0]; __syncthreads();
  float lsum = 0.f;
#pragma unroll
  for (int q = 0; q < 4; q++) {
    int a = t + q * 256;
    v[q] = (a < 1000) ? expf(v[q] - mx) : 0.f;
    lsum += v[q];
  }
  red[t] = lsum; __syncthreads();
  for (int s = 128; s > 0; s >>= 1) { if (t < s) red[t] += red[t + s]; __syncthreads(); }
  float inv = 1.f / red[0];
#pragma unroll
  for (int q = 0; q < 4; q++) {
    int a = t + q * 256;
    if (a < 1000) out[b * 1000 + a] = v[q] * inv;
  }
}

// ---------------------------------------------------------------------------
extern "C" void kernel_launch(void* const* d_in, const int* in_sizes, int n_in,
                              void* d_out, int out_size, void* d_ws, size_t ws_size,
                              hipStream_t stream)
{
  const float* image    = (const float*)d_in[0];
  const float* concepts = (const float*)d_in[1];
  const float* conv1_w  = (const float*)d_in[2];
  const float* conv1_b  = (const float*)d_in[3];
  const float* conv2_w  = (const float*)d_in[4];
  const float* conv2_b  = (const float*)d_in[5];
  const float* Wci      = (const float*)d_in[6];
  const float* bci      = (const float*)d_in[7];
  const float* Wu       = (const float*)d_in[8];
  const float* bu       = (const float*)d_in[9];
  const float* caw      = (const float*)d_in[10];
  const float* Wk       = (const float*)d_in[12];
  const float* bk       = (const float*)d_in[13];
  const float* Wm       = (const float*)d_in[14];
  const float* bm       = (const float*)d_in[15];
  const float* Wcat     = (const float*)d_in[16];
  const float* bcat     = (const float*)d_in[17];
  const float* Wcat2    = (const float*)d_in[18];
  const float* bcat2    = (const float*)d_in[19];
  const float* raw      = (const float*)d_in[20];
  const float* Wwrite   = (const float*)d_in[22];
  const float* bwrite   = (const float*)d_in[23];
  const float* initc    = (const float*)d_in[24];
  const float* initm    = (const float*)d_in[25];
  const float* Wproj    = (const float*)d_in[26];
  const float* bproj    = (const float*)d_in[27];
  const float* oaw      = (const float*)d_in[28];
  const float* labels   = (const float*)d_in[30];

  char* ws = (char*)d_ws;
  const size_t OFF_KNOW = 0;
  const size_t OFF_XPAD = 51380224;
  const size_t SZ_XPAD  = 83951616;
  const size_t OFF_W    = OFF_XPAD + SZ_XPAD;
  const size_t OFF_WKT  = OFF_W + 14155776;
  const size_t OFF_WC2T = OFF_WKT + 524288;
  size_t off = OFF_WC2T + 524288;
  auto allocB = [&](size_t bytes) {
    void* p = ws + off; off += (bytes + 255) & ~(size_t)255; return p;
  };
  ushort* know   = (ushort*)(ws + OFF_KNOW);
  ushort* imgpad = (ushort*)(ws + OFF_KNOW);                 // stem only
  ushort* xpad1  = (ushort*)(ws + OFF_XPAD);                 // stem only
  ushort* kproj  = (ushort*)(ws + OFF_XPAD);                 // loop
  ushort* befft  = (ushort*)(ws + OFF_XPAD + 51380224);      // loop, 16.78MB
  float*  rl     = (float*) (ws + OFF_XPAD + 68157440);      // loop, 0.2MB
  ushort* w1b    = (ushort*)(ws + OFF_W);
  ushort* w2b    = (ushort*)(ws + OFF_W);
  ushort* wkt    = (ushort*)(ws + OFF_WKT);
  ushort* wc2t   = (ushort*)(ws + OFF_WC2T);
  float* ipart  = (float*)allocB((size_t)BATCH * NCH * DM * 4);
  float* cbuf   = (float*)allocB(BATCH * DM * 4);
  float* mbufA  = (float*)allocB(BATCH * DM * 4);
  float* mbufB  = (float*)allocB(BATCH * DM * 4);
  float* mp     = (float*)allocB(BATCH * DM * 4);
  float* mw     = (float*)allocB(BATCH * 300 * 4);
  float* logits = (float*)allocB(BATCH * 1000 * 4);
  if (off > ws_size) return;  // graceful fail

  const int FUSED_LDS = 64 * ILS * 2 + 64 * 8 * 4;  // 68,608 B -> 2 blocks/CU
  hipFuncSetAttribute((const void*)k_fused12,
                      hipFuncAttributeMaxDynamicSharedMemorySize, FUSED_LDS);

  // --- stem ---
  k_zero<<<4096, 256, 0, stream>>>((uint4*)imgpad, 2625536L);
  k_zero<<<4096, 256, 0, stream>>>((uint4*)xpad1, 5246976L);
  k_padimg<<<dim3(BATCH, 49), 256, 0, stream>>>(image, imgpad);
  k_cvtw<256><<<512, 256, 0, stream>>>(conv1_w, w1b);
  k_cvtT<<<1024, 256, 0, stream>>>(Wk, wkt);
  k_cvtT<<<1024, 256, 0, stream>>>(Wcat2, wc2t);
  k_convm<256, 1><<<1664, 256, 0, stream>>>(w1b, imgpad, conv1_b, xpad1);
  k_cvtw<512><<<512, 256, 0, stream>>>(conv2_w, w2b);
  k_convm<512, 0><<<1664, 256, 0, stream>>>(w2b, xpad1, conv2_b, know);
  k_gemmm<<<1664, 256, 0, stream>>>(know, wkt, bk, kproj);
  k_init<<<BATCH, DM, 0, stream>>>(initc, initm, cbuf, mbufA);

  float* mc = mbufA; float* mn = mbufB;
  for (int i = 0; i < NSTEP; i++) {
    k_ctrl<<<BATCH, 512, 0, stream>>>(cbuf, mc, Wci, bci,
                                      Wu + (size_t)i * DM * DM, bu + i * DM,
                                      caw, concepts, Wm, bm, cbuf, mp);
    k_prefold<<<dim3(8, 8, 4), 256, 0, stream>>>(Wcat, mp, befft);
    k_fused12<<<dim3(800), 512, FUSED_LDS, stream>>>(
        kproj, befft, wc2t, bcat, bcat2, cbuf, raw, rl);
    k_softinfo<<<dim3(BATCH, NCH), 256, 0, stream>>>(rl, know, ipart);
    k_write<<<dim3(BATCH, 2), 256, 0, stream>>>(mc, ipart, Wwrite, bwrite, mn);
    float* tswap = mc; mc = mn; mn = tswap;
  }

  k_mpo<<<BATCH, 320, 0, stream>>>(mc, Wproj, bproj, oaw, mw);
  k_logits<<<dim3(BATCH, 4), 256, 0, stream>>>(mw, labels, logits);
  k_softmax_out<<<BATCH, 256, 0, stream>>>(logits, (float*)d_out);

  (void)in_sizes; (void)n_in; (void)out_size;
}